// Round 1
// baseline (10405.406 us; speedup 1.0000x reference)
//
#include <hip/hip_runtime.h>
#include <cstdint>
#include <cstddef>

// ---------------------------------------------------------------------------
// MambaFusion: 4-layer bidirectional Mamba over fused sensor tokens.
// bz=16, T=962, M=15392, C=384, DI=768, DSTATE=16, DTR=24.
// fp32 throughout (correctness-first baseline; CDNA4 has no fp32 MFMA).
// Workspace layout (floats), total ~240.0 MB — all buffers re-initialized
// every call (harness poisons ws with 0xAA):
//   x[M*C] | xfc1[M*C] | fc2b[M*C] | fm[M*C] | xz[M*1536] | xc[M*768]
//   | xdbl[M*56] | stats[M*2]
// ---------------------------------------------------------------------------

constexpr int BZv = 16, SEQ = 5, NV = 1;
constexpr int C = 384, DSTATE = 16, DCONV = 4, NLAYER = 4;
constexpr int DI = 768;                    // EXPAND*C
constexpr int DTR = 24;                    // ceil(C/16)
constexpr int NTOK = (NV + 2) * SEQ * 64;  // 960
constexpr int T = NTOK + 2;                // 962
constexpr int M = BZv * T;                 // 15392
constexpr int XZdim = 2 * DI;              // 1536
constexpr int ND = DTR + 2 * DSTATE;       // 56
constexpr size_t SEC_SZ = (size_t)BZv * SEQ * C * 64;  // 1,966,080 per output tensor

// ------------------------------ token assembly -----------------------------
__global__ __launch_bounds__(256) void assemble_k(
    const float* __restrict__ img, const float* __restrict__ lid,
    const float* __restrict__ rad, const float* __restrict__ gps,
    const float* __restrict__ pe, float* __restrict__ x) {
  int idx = blockIdx.x * 256 + threadIdx.x;  // [0, M*C)
  int c = idx % C;
  int m = idx / C;
  int b = m / T, t = m - b * T;
  float v;
  if (t < NTOK) {
    int g_ = t >> 6, p = t & 63;
    int sec = g_ / 5, s = g_ % 5;
    int band = (c < 128) ? 0 : (c < 256 ? 1 : 2);
    int which = (band + sec) % 3;  // 0=img 1=lid 2=rad
    const float* src = (which == 0) ? img : (which == 1 ? lid : rad);
    v = src[(((size_t)(b * 5 + s) * C + c) << 6) + p];
  } else {
    v = gps[((size_t)b * 2 + (t - NTOK)) * C + c];
  }
  x[idx] = v + pe[(size_t)t * C + c];
}

// ------------------------------ LN row stats -------------------------------
__global__ __launch_bounds__(256) void ln_stats_k(const float* __restrict__ x,
                                                  float* __restrict__ stats) {
  int row = blockIdx.x * 4 + (threadIdx.x >> 6);
  int lane = threadIdx.x & 63;
  const float* xr = x + (size_t)row * C;
  float v[6];
  float s = 0.f;
#pragma unroll
  for (int j = 0; j < 6; j++) {
    v[j] = xr[lane + 64 * j];
    s += v[j];
  }
#pragma unroll
  for (int o = 32; o > 0; o >>= 1) s += __shfl_xor(s, o, 64);
  float mean = s * (1.f / 384.f);
  float q = 0.f;
#pragma unroll
  for (int j = 0; j < 6; j++) {
    float d = v[j] - mean;
    q += d * d;
  }
#pragma unroll
  for (int o = 32; o > 0; o >>= 1) q += __shfl_xor(q, o, 64);
  if (lane == 0) {
    stats[2 * row] = mean;
    stats[2 * row + 1] = rsqrtf(q * (1.f / 384.f) + 1e-5f);
  }
}

// --------------------------------- GEMM ------------------------------------
// out[m,n] = sum_k A[srcrow(m), acol+k] * W[n,k]  (+bias)(+act)
// AMODE: 0 plain, 1 layernorm-on-load (stats,g,b). FLIPA: time-reverse rows.
// ACT: 0 none, 1 leaky-relu(0.2), 2 softplus, 3 combine: v*(e1+e2) (ldc==C).
template <int BM, int BN, int BK, int TM, int TN, int AMODE, int ACT, bool BIAS,
          bool FLIPA>
__global__ __launch_bounds__((BM / TM) * (BN / TN)) void gemm_k(
    const float* __restrict__ A, int lda, const float* __restrict__ W, int N,
    int K, const float* __restrict__ bias, float* __restrict__ Co, int ldc,
    const float* __restrict__ stats, const float* __restrict__ lng,
    const float* __restrict__ lnb, const float* __restrict__ e1,
    const float* __restrict__ e2) {
  constexpr int NT = (BM / TM) * (BN / TN);
  constexpr int BNT = BN / TN;
  __shared__ float As[BK][BM + 4];
  __shared__ float Bs[BK][BN + 4];
  const int tid = threadIdx.x;
  const int m0 = blockIdx.y * BM, n0 = blockIdx.x * BN;
  const int tx = tid % BNT, ty = tid / BNT;
  float acc[TM][TN];
#pragma unroll
  for (int i = 0; i < TM; i++)
#pragma unroll
    for (int j = 0; j < TN; j++) acc[i][j] = 0.f;

  constexpr int KT = BK / 4;      // float4 groups per LDS row
  const int lr = tid / KT;        // row within one pass
  const int lk = (tid % KT) * 4;  // k offset
  constexpr int ROWS = NT / KT;   // rows loaded per pass

  for (int k0 = 0; k0 < K; k0 += BK) {
#pragma unroll
    for (int p = 0; p < BM / ROWS; p++) {
      int r = p * ROWS + lr;
      int gm = m0 + r;
      float4 v = make_float4(0.f, 0.f, 0.f, 0.f);
      if (gm < M && (k0 + lk) < K) {
        int sm = gm;
        if (FLIPA) {
          int bb = gm / T;
          int tt = gm - bb * T;
          sm = bb * T + (T - 1 - tt);
        }
        v = *(const float4*)(A + (size_t)sm * lda + (k0 + lk));
        if constexpr (AMODE == 1) {
          float mean = stats[2 * gm], rstd = stats[2 * gm + 1];
          float4 gg = *(const float4*)(lng + k0 + lk);
          float4 bb4 = *(const float4*)(lnb + k0 + lk);
          v.x = (v.x - mean) * rstd * gg.x + bb4.x;
          v.y = (v.y - mean) * rstd * gg.y + bb4.y;
          v.z = (v.z - mean) * rstd * gg.z + bb4.z;
          v.w = (v.w - mean) * rstd * gg.w + bb4.w;
        }
      }
      As[lk + 0][r] = v.x;
      As[lk + 1][r] = v.y;
      As[lk + 2][r] = v.z;
      As[lk + 3][r] = v.w;
    }
#pragma unroll
    for (int p = 0; p < BN / ROWS; p++) {
      int r = p * ROWS + lr;
      int gn = n0 + r;
      float4 v = make_float4(0.f, 0.f, 0.f, 0.f);
      if (gn < N && (k0 + lk) < K)
        v = *(const float4*)(W + (size_t)gn * K + (k0 + lk));
      Bs[lk + 0][r] = v.x;
      Bs[lk + 1][r] = v.y;
      Bs[lk + 2][r] = v.z;
      Bs[lk + 3][r] = v.w;
    }
    __syncthreads();
#pragma unroll
    for (int kk = 0; kk < BK; kk++) {
      float af[TM], bf[TN];
#pragma unroll
      for (int i = 0; i < TM; i++) af[i] = As[kk][ty * TM + i];
#pragma unroll
      for (int j = 0; j < TN; j++) bf[j] = Bs[kk][tx * TN + j];
#pragma unroll
      for (int i = 0; i < TM; i++)
#pragma unroll
        for (int j = 0; j < TN; j++) acc[i][j] += af[i] * bf[j];
    }
    __syncthreads();
  }
#pragma unroll
  for (int i = 0; i < TM; i++) {
    int gm = m0 + ty * TM + i;
    if (gm >= M) continue;
#pragma unroll
    for (int j = 0; j < TN; j++) {
      int gn = n0 + tx * TN + j;
      if (gn >= N) continue;
      float v = acc[i][j];
      if constexpr (BIAS) v += bias[gn];
      if constexpr (ACT == 1) {
        v = v >= 0.f ? v : 0.2f * v;
      } else if constexpr (ACT == 2) {
        v = (v > 20.f) ? v : log1pf(expf(v));
      } else if constexpr (ACT == 3) {
        size_t o = (size_t)gm * C + gn;
        v = v * (e1[o] + e2[o]);
      }
      Co[(size_t)gm * ldc + gn] = v;
    }
  }
}

// --------------------------- depthwise conv + silu -------------------------
__global__ __launch_bounds__(256) void conv_k(const float* __restrict__ xz,
                                              const float* __restrict__ cw,
                                              const float* __restrict__ cb,
                                              float* __restrict__ xc) {
  int idx = blockIdx.x * 256 + threadIdx.x;  // [0, M*DI)
  int d = idx % DI;
  int m = idx / DI;
  int b = m / T, t = m - b * T;
  const float* base = xz + (size_t)b * T * XZdim + d;
  float a = cb[d];
#pragma unroll
  for (int j = 0; j < 4; j++) {
    int tt = t - 3 + j;
    if (tt >= 0) a += base[(size_t)tt * XZdim] * cw[d * 4 + j];
  }
  xc[(size_t)m * DI + d] = a / (1.f + __expf(-a));
}

// ------------------------------ selective scan -----------------------------
// Thread per (b,d); h[16] in registers; 962 sequential steps.
// Reads dt from xz[:, :768] (dt_proj overwrote dead xh), z from xz[:, 768:],
// xc in; writes gated y in-place into xc.
__global__ __launch_bounds__(256) void scan_k(const float* __restrict__ xzb,
                                              float* __restrict__ xcb,
                                              const float* __restrict__ xdbl,
                                              const float* __restrict__ alog,
                                              const float* __restrict__ Dp) {
  int b = blockIdx.x / 3;
  int d = (blockIdx.x % 3) * 256 + threadIdx.x;
  float A[DSTATE], h[DSTATE];
#pragma unroll
  for (int s = 0; s < DSTATE; s++) {
    A[s] = -expf(alog[d * DSTATE + s]);
    h[s] = 0.f;
  }
  float Dd = Dp[d];
  const float* xzr = xzb + (size_t)b * T * XZdim;
  float* xcr = xcb + (size_t)b * T * DI;
  const float* xdr = xdbl + (size_t)b * T * ND;
  for (int t = 0; t < T; t++) {
    float dt = xzr[(size_t)t * XZdim + d];
    float xv = xcr[(size_t)t * DI + d];
    float zv = xzr[(size_t)t * XZdim + DI + d];
    float dx = dt * xv;
    float accv = 0.f;
    const float* bc = xdr + (size_t)t * ND;
#pragma unroll
    for (int s = 0; s < DSTATE; s++) {
      float e = __expf(dt * A[s]);
      h[s] = h[s] * e + dx * bc[DTR + s];
      accv += h[s] * bc[DTR + DSTATE + s];
    }
    float y = accv + Dd * xv;
    float sz = zv / (1.f + __expf(-zv));
    xcr[(size_t)t * DI + d] = y * sz;
  }
}

// --------------------------- final LN + scatter ----------------------------
__device__ __forceinline__ size_t out_index(int b, int t, int c) {
  if (t < NTOK) {
    int g_ = t >> 6, p = t & 63;
    int sec = g_ / 5, s = g_ % 5;
    return (size_t)sec * SEC_SZ + (((size_t)(b * 5 + s) * C + c) << 6) + p;
  }
  return 3 * SEC_SZ + ((size_t)b * 2 + (t - NTOK)) * C + c;
}

__global__ __launch_bounds__(128) void ln_scatter_k(const float* __restrict__ x,
                                                    const float* __restrict__ g,
                                                    const float* __restrict__ bb,
                                                    float* __restrict__ out) {
  int m = blockIdx.x, tid = threadIdx.x;
  int b = m / T, t = m - b * T;
  const float* xr = x + (size_t)m * C;
  float v0 = xr[tid], v1 = xr[tid + 128], v2 = xr[tid + 256];
  __shared__ float sm2[2];
  int wid = tid >> 6, lane = tid & 63;
  float s = v0 + v1 + v2;
#pragma unroll
  for (int o = 32; o > 0; o >>= 1) s += __shfl_xor(s, o, 64);
  if (lane == 0) sm2[wid] = s;
  __syncthreads();
  float mean = (sm2[0] + sm2[1]) * (1.f / 384.f);
  __syncthreads();
  float d0 = v0 - mean, d1 = v1 - mean, d2 = v2 - mean;
  float q = d0 * d0 + d1 * d1 + d2 * d2;
#pragma unroll
  for (int o = 32; o > 0; o >>= 1) q += __shfl_xor(q, o, 64);
  if (lane == 0) sm2[wid] = q;
  __syncthreads();
  float rstd = rsqrtf((sm2[0] + sm2[1]) * (1.f / 384.f) + 1e-5f);
  float vv[3] = {v0, v1, v2};
#pragma unroll
  for (int j = 0; j < 3; j++) {
    int c = tid + j * 128;
    out[out_index(b, t, c)] = (vv[j] - mean) * rstd * g[c] + bb[c];
  }
}

// --------------------------------- launch ----------------------------------
extern "C" void kernel_launch(void* const* d_in, const int* in_sizes, int n_in,
                              void* d_out, int out_size, void* d_ws,
                              size_t ws_size, hipStream_t stream) {
  const float* image = (const float*)d_in[0];
  const float* lidar = (const float*)d_in[1];
  const float* radar = (const float*)d_in[2];
  const float* gps = (const float*)d_in[3];
  const float* pe = (const float*)d_in[4];
  const float* ln1g = (const float*)d_in[5];
  const float* ln1b = (const float*)d_in[6];
  const float* fc1w = (const float*)d_in[7];
  const float* fc1b = (const float*)d_in[8];
  const float* fc2w = (const float*)d_in[9];
  const float* fc2b_ = (const float*)d_in[10];
  const float* inw = (const float*)d_in[11];
  const float* cw = (const float*)d_in[12];
  const float* cb = (const float*)d_in[13];
  const float* xw = (const float*)d_in[14];
  const float* dtw = (const float*)d_in[15];
  const float* dtb = (const float*)d_in[16];
  const float* alog = (const float*)d_in[17];
  const float* Dp = (const float*)d_in[18];
  const float* ow = (const float*)d_in[19];
  const float* lnfg = (const float*)d_in[20];
  const float* lnfb = (const float*)d_in[21];
  float* out = (float*)d_out;

  float* ws = (float*)d_ws;
  float* x = ws;
  float* xfc1 = x + (size_t)M * C;
  float* fcb = xfc1 + (size_t)M * C;
  float* fm = fcb + (size_t)M * C;
  float* xz = fm + (size_t)M * C;
  float* xc = xz + (size_t)M * XZdim;
  float* xdbl = xc + (size_t)M * DI;
  float* stats = xdbl + (size_t)M * ND;

  assemble_k<<<(M * C) / 256, 256, 0, stream>>>(image, lidar, radar, gps, pe, x);

  for (int l = 0; l < NLAYER; l++) {
    ln_stats_k<<<M / 4, 256, 0, stream>>>(x, stats);
    // fc1 = LN(x) @ fc1_w^T + b
    gemm_k<128, 128, 16, 8, 8, 1, 0, true, false>
        <<<dim3(3, 121), 256, 0, stream>>>(x, C, fc1w + (size_t)l * C * C, C, C,
                                           fc1b + l * C, xfc1, C, stats,
                                           ln1g + l * C, ln1b + l * C, nullptr,
                                           nullptr);
    // fc2b = lrelu(flip(xfc1) @ fc2_w^T + b)
    gemm_k<128, 128, 16, 8, 8, 0, 1, true, true>
        <<<dim3(3, 121), 256, 0, stream>>>(xfc1, C, fc2w + (size_t)l * C * C, C,
                                           C, fc2b_ + l * C, fcb, C, nullptr,
                                           nullptr, nullptr, nullptr, nullptr);
    for (int dir = 0; dir < 2; dir++) {
      size_t wo = (size_t)(l * 2 + dir);
      // in_proj -> xz (dir1 reads time-flipped rows; downstream stays flipped)
      if (dir == 0)
        gemm_k<128, 128, 16, 8, 8, 0, 0, false, false>
            <<<dim3(12, 121), 256, 0, stream>>>(
                xfc1, C, inw + wo * 2 * DI * C, 2 * DI, C, nullptr, xz, XZdim,
                nullptr, nullptr, nullptr, nullptr, nullptr);
      else
        gemm_k<128, 128, 16, 8, 8, 0, 0, false, true>
            <<<dim3(12, 121), 256, 0, stream>>>(
                xfc1, C, inw + wo * 2 * DI * C, 2 * DI, C, nullptr, xz, XZdim,
                nullptr, nullptr, nullptr, nullptr, nullptr);
      // causal depthwise conv + silu -> xc
      conv_k<<<(M * DI) / 256, 256, 0, stream>>>(xz, cw + wo * DI * DCONV,
                                                 cb + wo * DI, xc);
      // x_proj -> xdbl (dt_r | B | C)
      gemm_k<64, 64, 16, 4, 4, 0, 0, false, false>
          <<<dim3(1, 241), 256, 0, stream>>>(xc, DI, xw + wo * ND * DI, ND, DI,
                                             nullptr, xdbl, ND, nullptr,
                                             nullptr, nullptr, nullptr, nullptr);
      // dt = softplus(dt_r @ dtw^T + dtb) -> overwrite dead xh half of xz
      gemm_k<128, 128, 16, 8, 8, 0, 2, true, false>
          <<<dim3(6, 121), 256, 0, stream>>>(xdbl, ND, dtw + wo * DI * DTR, DI,
                                             DTR, dtb + wo * DI, xz, XZdim,
                                             nullptr, nullptr, nullptr, nullptr,
                                             nullptr);
      // selective scan (+D*xc, *silu(z)) in-place into xc
      scan_k<<<BZv * 3, 256, 0, stream>>>(xz, xc, xdbl, alog + wo * DI * DSTATE,
                                          Dp + wo * DI);
      // out_proj; dir1 fuses the combine x = bm*(lrelu_fc2 + fm)
      if (dir == 0)
        gemm_k<128, 128, 16, 8, 8, 0, 0, false, false>
            <<<dim3(3, 121), 256, 0, stream>>>(xc, DI, ow + wo * C * DI, C, DI,
                                               nullptr, fm, C, nullptr, nullptr,
                                               nullptr, nullptr, nullptr);
      else
        gemm_k<128, 128, 16, 8, 8, 0, 3, false, false>
            <<<dim3(3, 121), 256, 0, stream>>>(xc, DI, ow + wo * C * DI, C, DI,
                                               nullptr, x, C, nullptr, nullptr,
                                               nullptr, fcb, fm);
    }
  }
  ln_scatter_k<<<M, 128, 0, stream>>>(x, lnfg, lnfb, out);
}

// Round 2
// 7192.540 us; speedup vs baseline: 1.4467x; 1.4467x over previous
//
#include <hip/hip_runtime.h>
#include <cstdint>
#include <cstddef>

// ---------------------------------------------------------------------------
// MambaFusion: 4-layer bidirectional Mamba over fused sensor tokens.
// bz=16, T=962, M=15392, C=384, DI=768, DSTATE=16, DTR=24.
// fp32 throughout. R1: chunked parallel selective scan (13 chunks x 74 steps,
// 3-phase: local scan -> chunk-state propagate -> rescan+gate). Chunk-state
// buffers alias the `x` residual buffer (dead between fc1 and the dir-1
// out_proj combine).
// Workspace layout (floats), ~240 MB:
//   x[M*C] | xfc1[M*C] | fc2b[M*C] | fm[M*C] | xz[M*1536] | xc[M*768]
//   | xdbl[M*56] | stats[M*2]
// ---------------------------------------------------------------------------

constexpr int BZv = 16, SEQ = 5, NV = 1;
constexpr int C = 384, DSTATE = 16, DCONV = 4, NLAYER = 4;
constexpr int DI = 768;                    // EXPAND*C
constexpr int DTR = 24;                    // ceil(C/16)
constexpr int NTOK = (NV + 2) * SEQ * 64;  // 960
constexpr int T = NTOK + 2;                // 962
constexpr int M = BZv * T;                 // 15392
constexpr int XZdim = 2 * DI;              // 1536
constexpr int ND = DTR + 2 * DSTATE;       // 56
constexpr int NCHUNK = 13, TC = 74;        // 13*74 == 962
constexpr size_t SEC_SZ = (size_t)BZv * SEQ * C * 64;  // per output tensor

// ------------------------------ token assembly -----------------------------
__global__ __launch_bounds__(256) void assemble_k(
    const float* __restrict__ img, const float* __restrict__ lid,
    const float* __restrict__ rad, const float* __restrict__ gps,
    const float* __restrict__ pe, float* __restrict__ x) {
  int idx = blockIdx.x * 256 + threadIdx.x;  // [0, M*C)
  int c = idx % C;
  int m = idx / C;
  int b = m / T, t = m - b * T;
  float v;
  if (t < NTOK) {
    int g_ = t >> 6, p = t & 63;
    int sec = g_ / 5, s = g_ % 5;
    int band = (c < 128) ? 0 : (c < 256 ? 1 : 2);
    int which = (band + sec) % 3;  // 0=img 1=lid 2=rad
    const float* src = (which == 0) ? img : (which == 1 ? lid : rad);
    v = src[(((size_t)(b * 5 + s) * C + c) << 6) + p];
  } else {
    v = gps[((size_t)b * 2 + (t - NTOK)) * C + c];
  }
  x[idx] = v + pe[(size_t)t * C + c];
}

// ------------------------------ LN row stats -------------------------------
__global__ __launch_bounds__(256) void ln_stats_k(const float* __restrict__ x,
                                                  float* __restrict__ stats) {
  int row = blockIdx.x * 4 + (threadIdx.x >> 6);
  int lane = threadIdx.x & 63;
  const float* xr = x + (size_t)row * C;
  float v[6];
  float s = 0.f;
#pragma unroll
  for (int j = 0; j < 6; j++) {
    v[j] = xr[lane + 64 * j];
    s += v[j];
  }
#pragma unroll
  for (int o = 32; o > 0; o >>= 1) s += __shfl_xor(s, o, 64);
  float mean = s * (1.f / 384.f);
  float q = 0.f;
#pragma unroll
  for (int j = 0; j < 6; j++) {
    float d = v[j] - mean;
    q += d * d;
  }
#pragma unroll
  for (int o = 32; o > 0; o >>= 1) q += __shfl_xor(q, o, 64);
  if (lane == 0) {
    stats[2 * row] = mean;
    stats[2 * row + 1] = rsqrtf(q * (1.f / 384.f) + 1e-5f);
  }
}

// --------------------------------- GEMM ------------------------------------
// out[m,n] = sum_k A[srcrow(m), acol+k] * W[n,k]  (+bias)(+act)
// AMODE: 0 plain, 1 layernorm-on-load (stats,g,b). FLIPA: time-reverse rows.
// ACT: 0 none, 1 leaky-relu(0.2), 2 softplus, 3 combine: v*(e1+e2) (ldc==C).
template <int BM, int BN, int BK, int TM, int TN, int AMODE, int ACT, bool BIAS,
          bool FLIPA>
__global__ __launch_bounds__((BM / TM) * (BN / TN)) void gemm_k(
    const float* __restrict__ A, int lda, const float* __restrict__ W, int N,
    int K, const float* __restrict__ bias, float* __restrict__ Co, int ldc,
    const float* __restrict__ stats, const float* __restrict__ lng,
    const float* __restrict__ lnb, const float* __restrict__ e1,
    const float* __restrict__ e2) {
  constexpr int NT = (BM / TM) * (BN / TN);
  constexpr int BNT = BN / TN;
  __shared__ float As[BK][BM + 4];
  __shared__ float Bs[BK][BN + 4];
  const int tid = threadIdx.x;
  const int m0 = blockIdx.y * BM, n0 = blockIdx.x * BN;
  const int tx = tid % BNT, ty = tid / BNT;
  float acc[TM][TN];
#pragma unroll
  for (int i = 0; i < TM; i++)
#pragma unroll
    for (int j = 0; j < TN; j++) acc[i][j] = 0.f;

  constexpr int KT = BK / 4;      // float4 groups per LDS row
  const int lr = tid / KT;        // row within one pass
  const int lk = (tid % KT) * 4;  // k offset
  constexpr int ROWS = NT / KT;   // rows loaded per pass

  for (int k0 = 0; k0 < K; k0 += BK) {
#pragma unroll
    for (int p = 0; p < BM / ROWS; p++) {
      int r = p * ROWS + lr;
      int gm = m0 + r;
      float4 v = make_float4(0.f, 0.f, 0.f, 0.f);
      if (gm < M && (k0 + lk) < K) {
        int sm = gm;
        if (FLIPA) {
          int bb = gm / T;
          int tt = gm - bb * T;
          sm = bb * T + (T - 1 - tt);
        }
        v = *(const float4*)(A + (size_t)sm * lda + (k0 + lk));
        if constexpr (AMODE == 1) {
          float mean = stats[2 * gm], rstd = stats[2 * gm + 1];
          float4 gg = *(const float4*)(lng + k0 + lk);
          float4 bb4 = *(const float4*)(lnb + k0 + lk);
          v.x = (v.x - mean) * rstd * gg.x + bb4.x;
          v.y = (v.y - mean) * rstd * gg.y + bb4.y;
          v.z = (v.z - mean) * rstd * gg.z + bb4.z;
          v.w = (v.w - mean) * rstd * gg.w + bb4.w;
        }
      }
      As[lk + 0][r] = v.x;
      As[lk + 1][r] = v.y;
      As[lk + 2][r] = v.z;
      As[lk + 3][r] = v.w;
    }
#pragma unroll
    for (int p = 0; p < BN / ROWS; p++) {
      int r = p * ROWS + lr;
      int gn = n0 + r;
      float4 v = make_float4(0.f, 0.f, 0.f, 0.f);
      if (gn < N && (k0 + lk) < K)
        v = *(const float4*)(W + (size_t)gn * K + (k0 + lk));
      Bs[lk + 0][r] = v.x;
      Bs[lk + 1][r] = v.y;
      Bs[lk + 2][r] = v.z;
      Bs[lk + 3][r] = v.w;
    }
    __syncthreads();
#pragma unroll
    for (int kk = 0; kk < BK; kk++) {
      float af[TM], bf[TN];
#pragma unroll
      for (int i = 0; i < TM; i++) af[i] = As[kk][ty * TM + i];
#pragma unroll
      for (int j = 0; j < TN; j++) bf[j] = Bs[kk][tx * TN + j];
#pragma unroll
      for (int i = 0; i < TM; i++)
#pragma unroll
        for (int j = 0; j < TN; j++) acc[i][j] += af[i] * bf[j];
    }
    __syncthreads();
  }
#pragma unroll
  for (int i = 0; i < TM; i++) {
    int gm = m0 + ty * TM + i;
    if (gm >= M) continue;
#pragma unroll
    for (int j = 0; j < TN; j++) {
      int gn = n0 + tx * TN + j;
      if (gn >= N) continue;
      float v = acc[i][j];
      if constexpr (BIAS) v += bias[gn];
      if constexpr (ACT == 1) {
        v = v >= 0.f ? v : 0.2f * v;
      } else if constexpr (ACT == 2) {
        v = (v > 20.f) ? v : log1pf(expf(v));
      } else if constexpr (ACT == 3) {
        size_t o = (size_t)gm * C + gn;
        v = v * (e1[o] + e2[o]);
      }
      Co[(size_t)gm * ldc + gn] = v;
    }
  }
}

// --------------------------- depthwise conv + silu -------------------------
__global__ __launch_bounds__(256) void conv_k(const float* __restrict__ xz,
                                              const float* __restrict__ cw,
                                              const float* __restrict__ cb,
                                              float* __restrict__ xc) {
  int idx = blockIdx.x * 256 + threadIdx.x;  // [0, M*DI)
  int d = idx % DI;
  int m = idx / DI;
  int b = m / T, t = m - b * T;
  const float* base = xz + (size_t)b * T * XZdim + d;
  float a = cb[d];
#pragma unroll
  for (int j = 0; j < 4; j++) {
    int tt = t - 3 + j;
    if (tt >= 0) a += base[(size_t)tt * XZdim] * cw[d * 4 + j];
  }
  xc[(size_t)m * DI + d] = a / (1.f + __expf(-a));
}

// ----------------------- chunked selective scan ----------------------------
// Recurrence h[s] <- exp(dt*A[s])*h[s] + dt*x*B[s] is linear in h, so it
// chunk-decomposes exactly. hchk/pchk layout: [b][chunk][s][d] (d coalesced).
// Phase 1: per-(b,chunk,d) local scan from h=0; stores h_local and the chunk
// decay P[s] = exp(A[s] * sum(dt)) (exact log-domain product).
__global__ __launch_bounds__(256) void scan_p1_k(
    const float* __restrict__ xzb, const float* __restrict__ xcb,
    const float* __restrict__ xdbl, const float* __restrict__ alog,
    float* __restrict__ hchk, float* __restrict__ pchk) {
  int d = blockIdx.x * 256 + threadIdx.x;
  int ch = blockIdx.y, b = blockIdx.z;
  float A[DSTATE], h[DSTATE];
#pragma unroll
  for (int s = 0; s < DSTATE; s++) {
    A[s] = -expf(alog[d * DSTATE + s]);
    h[s] = 0.f;
  }
  const int t0 = ch * TC;
  const float* xzr = xzb + ((size_t)b * T + t0) * XZdim;
  const float* xcr = xcb + ((size_t)b * T + t0) * DI;
  const float* xdr = xdbl + ((size_t)b * T + t0) * ND;
  float sdt = 0.f;
  for (int t = 0; t < TC; t++) {
    float dt = xzr[(size_t)t * XZdim + d];
    float xv = xcr[(size_t)t * DI + d];
    float dx = dt * xv;
    const float* bvec = xdr + (size_t)t * ND + DTR;
    sdt += dt;
#pragma unroll
    for (int s = 0; s < DSTATE; s++) {
      float e = __expf(dt * A[s]);
      h[s] = h[s] * e + dx * bvec[s];
    }
  }
  size_t o = ((size_t)(b * NCHUNK + ch) * DSTATE) * DI + d;
#pragma unroll
  for (int s = 0; s < DSTATE; s++) {
    hchk[o + (size_t)s * DI] = h[s];
    pchk[o + (size_t)s * DI] = __expf(A[s] * sdt);
  }
}

// Phase 2: per-(b,d), sequential over the 13 chunks: replace hchk[b][ch] with
// the state ENTERING chunk ch.
__global__ __launch_bounds__(256) void scan_p2_k(float* __restrict__ hchk,
                                                 const float* __restrict__ pchk) {
  int idx = blockIdx.x * 256 + threadIdx.x;  // [0, BZv*DI)
  int b = idx / DI, d = idx - b * DI;
  float hin[DSTATE];
#pragma unroll
  for (int s = 0; s < DSTATE; s++) hin[s] = 0.f;
  for (int ch = 0; ch < NCHUNK; ch++) {
    size_t o = ((size_t)(b * NCHUNK + ch) * DSTATE) * DI + d;
#pragma unroll
    for (int s = 0; s < DSTATE; s++) {
      float P = pchk[o + (size_t)s * DI];
      float hl = hchk[o + (size_t)s * DI];
      hchk[o + (size_t)s * DI] = hin[s];
      hin[s] = P * hin[s] + hl;
    }
  }
}

// Phase 3: rescan each chunk from its true incoming state; emit
// y = h.C + D*x, gated by silu(z), in-place into xc.
__global__ __launch_bounds__(256) void scan_p3_k(
    const float* __restrict__ xzb, float* __restrict__ xcb,
    const float* __restrict__ xdbl, const float* __restrict__ alog,
    const float* __restrict__ Dp, const float* __restrict__ hchk) {
  int d = blockIdx.x * 256 + threadIdx.x;
  int ch = blockIdx.y, b = blockIdx.z;
  float A[DSTATE], h[DSTATE];
  size_t o = ((size_t)(b * NCHUNK + ch) * DSTATE) * DI + d;
#pragma unroll
  for (int s = 0; s < DSTATE; s++) {
    A[s] = -expf(alog[d * DSTATE + s]);
    h[s] = hchk[o + (size_t)s * DI];
  }
  float Dd = Dp[d];
  const int t0 = ch * TC;
  const float* xzr = xzb + ((size_t)b * T + t0) * XZdim;
  float* xcr = xcb + ((size_t)b * T + t0) * DI;
  const float* xdr = xdbl + ((size_t)b * T + t0) * ND;
  for (int t = 0; t < TC; t++) {
    float dt = xzr[(size_t)t * XZdim + d];
    float xv = xcr[(size_t)t * DI + d];
    float zv = xzr[(size_t)t * XZdim + DI + d];
    float dx = dt * xv;
    float accv = 0.f;
    const float* bc = xdr + (size_t)t * ND + DTR;
#pragma unroll
    for (int s = 0; s < DSTATE; s++) {
      float e = __expf(dt * A[s]);
      h[s] = h[s] * e + dx * bc[s];
      accv += h[s] * bc[DSTATE + s];
    }
    float y = accv + Dd * xv;
    float sz = zv / (1.f + __expf(-zv));
    xcr[(size_t)t * DI + d] = y * sz;
  }
}

// --------------------------- final LN + scatter ----------------------------
__device__ __forceinline__ size_t out_index(int b, int t, int c) {
  if (t < NTOK) {
    int g_ = t >> 6, p = t & 63;
    int sec = g_ / 5, s = g_ % 5;
    return (size_t)sec * SEC_SZ + (((size_t)(b * 5 + s) * C + c) << 6) + p;
  }
  return 3 * SEC_SZ + ((size_t)b * 2 + (t - NTOK)) * C + c;
}

__global__ __launch_bounds__(128) void ln_scatter_k(const float* __restrict__ x,
                                                    const float* __restrict__ g,
                                                    const float* __restrict__ bb,
                                                    float* __restrict__ out) {
  int m = blockIdx.x, tid = threadIdx.x;
  int b = m / T, t = m - b * T;
  const float* xr = x + (size_t)m * C;
  float v0 = xr[tid], v1 = xr[tid + 128], v2 = xr[tid + 256];
  __shared__ float sm2[2];
  int wid = tid >> 6, lane = tid & 63;
  float s = v0 + v1 + v2;
#pragma unroll
  for (int o = 32; o > 0; o >>= 1) s += __shfl_xor(s, o, 64);
  if (lane == 0) sm2[wid] = s;
  __syncthreads();
  float mean = (sm2[0] + sm2[1]) * (1.f / 384.f);
  __syncthreads();
  float d0 = v0 - mean, d1 = v1 - mean, d2 = v2 - mean;
  float q = d0 * d0 + d1 * d1 + d2 * d2;
#pragma unroll
  for (int o = 32; o > 0; o >>= 1) q += __shfl_xor(q, o, 64);
  if (lane == 0) sm2[wid] = q;
  __syncthreads();
  float rstd = rsqrtf((sm2[0] + sm2[1]) * (1.f / 384.f) + 1e-5f);
  float vv[3] = {v0, v1, v2};
#pragma unroll
  for (int j = 0; j < 3; j++) {
    int c = tid + j * 128;
    out[out_index(b, t, c)] = (vv[j] - mean) * rstd * g[c] + bb[c];
  }
}

// --------------------------------- launch ----------------------------------
extern "C" void kernel_launch(void* const* d_in, const int* in_sizes, int n_in,
                              void* d_out, int out_size, void* d_ws,
                              size_t ws_size, hipStream_t stream) {
  const float* image = (const float*)d_in[0];
  const float* lidar = (const float*)d_in[1];
  const float* radar = (const float*)d_in[2];
  const float* gps = (const float*)d_in[3];
  const float* pe = (const float*)d_in[4];
  const float* ln1g = (const float*)d_in[5];
  const float* ln1b = (const float*)d_in[6];
  const float* fc1w = (const float*)d_in[7];
  const float* fc1b = (const float*)d_in[8];
  const float* fc2w = (const float*)d_in[9];
  const float* fc2b_ = (const float*)d_in[10];
  const float* inw = (const float*)d_in[11];
  const float* cw = (const float*)d_in[12];
  const float* cb = (const float*)d_in[13];
  const float* xw = (const float*)d_in[14];
  const float* dtw = (const float*)d_in[15];
  const float* dtb = (const float*)d_in[16];
  const float* alog = (const float*)d_in[17];
  const float* Dp = (const float*)d_in[18];
  const float* ow = (const float*)d_in[19];
  const float* lnfg = (const float*)d_in[20];
  const float* lnfb = (const float*)d_in[21];
  float* out = (float*)d_out;

  float* ws = (float*)d_ws;
  float* x = ws;
  float* xfc1 = x + (size_t)M * C;
  float* fcb = xfc1 + (size_t)M * C;
  float* fm = fcb + (size_t)M * C;
  float* xz = fm + (size_t)M * C;
  float* xc = xz + (size_t)M * XZdim;
  float* xdbl = xc + (size_t)M * DI;
  float* stats = xdbl + (size_t)M * ND;
  // Chunk-state buffers alias x (dead between fc1-read and dir-1 out_proj
  // write): 2 * BZ*NCHUNK*DSTATE*DI = 5,111,808 floats <= M*C = 5,910,528.
  constexpr size_t CHK_ELEMS = (size_t)BZv * NCHUNK * DSTATE * DI;
  float* hchk = x;
  float* pchk = x + CHK_ELEMS;

  assemble_k<<<(M * C) / 256, 256, 0, stream>>>(image, lidar, radar, gps, pe, x);

  for (int l = 0; l < NLAYER; l++) {
    ln_stats_k<<<M / 4, 256, 0, stream>>>(x, stats);
    // fc1 = LN(x) @ fc1_w^T + b
    gemm_k<128, 128, 16, 8, 8, 1, 0, true, false>
        <<<dim3(3, 121), 256, 0, stream>>>(x, C, fc1w + (size_t)l * C * C, C, C,
                                           fc1b + l * C, xfc1, C, stats,
                                           ln1g + l * C, ln1b + l * C, nullptr,
                                           nullptr);
    // fc2b = lrelu(flip(xfc1) @ fc2_w^T + b)
    gemm_k<128, 128, 16, 8, 8, 0, 1, true, true>
        <<<dim3(3, 121), 256, 0, stream>>>(xfc1, C, fc2w + (size_t)l * C * C, C,
                                           C, fc2b_ + l * C, fcb, C, nullptr,
                                           nullptr, nullptr, nullptr, nullptr);
    for (int dir = 0; dir < 2; dir++) {
      size_t wo = (size_t)(l * 2 + dir);
      // in_proj -> xz (dir1 reads time-flipped rows; downstream stays flipped)
      if (dir == 0)
        gemm_k<128, 128, 16, 8, 8, 0, 0, false, false>
            <<<dim3(12, 121), 256, 0, stream>>>(
                xfc1, C, inw + wo * 2 * DI * C, 2 * DI, C, nullptr, xz, XZdim,
                nullptr, nullptr, nullptr, nullptr, nullptr);
      else
        gemm_k<128, 128, 16, 8, 8, 0, 0, false, true>
            <<<dim3(12, 121), 256, 0, stream>>>(
                xfc1, C, inw + wo * 2 * DI * C, 2 * DI, C, nullptr, xz, XZdim,
                nullptr, nullptr, nullptr, nullptr, nullptr);
      // causal depthwise conv + silu -> xc
      conv_k<<<(M * DI) / 256, 256, 0, stream>>>(xz, cw + wo * DI * DCONV,
                                                 cb + wo * DI, xc);
      // x_proj -> xdbl (dt_r | B | C)
      gemm_k<64, 64, 16, 4, 4, 0, 0, false, false>
          <<<dim3(1, 241), 256, 0, stream>>>(xc, DI, xw + wo * ND * DI, ND, DI,
                                             nullptr, xdbl, ND, nullptr,
                                             nullptr, nullptr, nullptr, nullptr);
      // dt = softplus(dt_r @ dtw^T + dtb) -> overwrite dead xh half of xz
      gemm_k<128, 128, 16, 8, 8, 0, 2, true, false>
          <<<dim3(6, 121), 256, 0, stream>>>(xdbl, ND, dtw + wo * DI * DTR, DI,
                                             DTR, dtb + wo * DI, xz, XZdim,
                                             nullptr, nullptr, nullptr, nullptr,
                                             nullptr);
      // chunked selective scan (+D*xc, *silu(z)) in-place into xc
      scan_p1_k<<<dim3(3, NCHUNK, BZv), 256, 0, stream>>>(
          xz, xc, xdbl, alog + wo * DI * DSTATE, hchk, pchk);
      scan_p2_k<<<(BZv * DI) / 256, 256, 0, stream>>>(hchk, pchk);
      scan_p3_k<<<dim3(3, NCHUNK, BZv), 256, 0, stream>>>(
          xz, xc, xdbl, alog + wo * DI * DSTATE, Dp + wo * DI, hchk);
      // out_proj; dir1 fuses the combine x = bm*(lrelu_fc2 + fm)
      if (dir == 0)
        gemm_k<128, 128, 16, 8, 8, 0, 0, false, false>
            <<<dim3(3, 121), 256, 0, stream>>>(xc, DI, ow + wo * C * DI, C, DI,
                                               nullptr, fm, C, nullptr, nullptr,
                                               nullptr, nullptr, nullptr);
      else
        gemm_k<128, 128, 16, 8, 8, 0, 3, false, false>
            <<<dim3(3, 121), 256, 0, stream>>>(xc, DI, ow + wo * C * DI, C, DI,
                                               nullptr, x, C, nullptr, nullptr,
                                               nullptr, fcb, fm);
    }
  }
  ln_scatter_k<<<M, 128, 0, stream>>>(x, lnfg, lnfb, out);
}

// Round 4
// 5626.740 us; speedup vs baseline: 1.8493x; 1.2783x over previous
//
#include <hip/hip_runtime.h>
#include <cstdint>
#include <cstddef>

// ---------------------------------------------------------------------------
// MambaFusion. R3: R2's split-bf16 MFMA GEMMs, restructured to fit the
// workspace (R2 needed 320 MB and aborted; proven bound is ~240 MB).
// - Per-direction mamba pipeline runs in 2 half-batches (HB=8, MH=7696):
//   xz/xc/xdbl/y/hchk are half-sized; GEMMs take arow_off/crow_off.
// - LN bf16 planes alias the fm region (disjoint lifetimes).
// - Total: 58,559,424 floats = 234.2 MB.
// ---------------------------------------------------------------------------

constexpr int BZv = 16, SEQ = 5, NV = 1;
constexpr int C = 384, DSTATE = 16, DCONV = 4, NLAYER = 4;
constexpr int DI = 768;
constexpr int DTR = 24;
constexpr int NTOK = (NV + 2) * SEQ * 64;  // 960
constexpr int T = NTOK + 2;                // 962
constexpr int M = BZv * T;                 // 15392
constexpr int HB = 8;                      // batches per half
constexpr int MH = HB * T;                 // 7696 rows per half
constexpr int XZdim = 2 * DI;              // 1536
constexpr int ND = DTR + 2 * DSTATE;       // 56
constexpr int NCHUNK = 13, TC = 74;
constexpr size_t SEC_SZ = (size_t)BZv * SEQ * C * 64;

typedef __attribute__((ext_vector_type(8))) short short8;
typedef __attribute__((ext_vector_type(4))) float floatx4;

#define GLOAD_LDS16(g, l)                                        \
  __builtin_amdgcn_global_load_lds(                              \
      (const __attribute__((address_space(1))) void*)(g),        \
      (__attribute__((address_space(3))) void*)(l), 16, 0, 0)

__device__ __forceinline__ void split_bf16(float v, short& hi, short& lo) {
  unsigned u = __float_as_uint(v);
  unsigned hib = u & 0xFFFF0000u;      // truncate to bf16
  float r = v - __uint_as_float(hib);  // exact residual
  hi = (short)(hib >> 16);
  lo = (short)(__float_as_uint(r) >> 16);
}

// ------------------------------ token assembly -----------------------------
__global__ __launch_bounds__(256) void assemble_k(
    const float* __restrict__ img, const float* __restrict__ lid,
    const float* __restrict__ rad, const float* __restrict__ gps,
    const float* __restrict__ pe, float* __restrict__ x) {
  int idx = blockIdx.x * 256 + threadIdx.x;
  int c = idx % C;
  int m = idx / C;
  int b = m / T, t = m - b * T;
  float v;
  if (t < NTOK) {
    int g_ = t >> 6, p = t & 63;
    int sec = g_ / 5, s = g_ % 5;
    int band = (c < 128) ? 0 : (c < 256 ? 1 : 2);
    int which = (band + sec) % 3;
    const float* src = (which == 0) ? img : (which == 1 ? lid : rad);
    v = src[(((size_t)(b * 5 + s) * C + c) << 6) + p];
  } else {
    v = gps[((size_t)b * 2 + (t - NTOK)) * C + c];
  }
  x[idx] = v + pe[(size_t)t * C + c];
}

// ------------------------------ LN row stats -------------------------------
__global__ __launch_bounds__(256) void ln_stats_k(const float* __restrict__ x,
                                                  float* __restrict__ stats) {
  int row = blockIdx.x * 4 + (threadIdx.x >> 6);
  int lane = threadIdx.x & 63;
  const float* xr = x + (size_t)row * C;
  float v[6];
  float s = 0.f;
#pragma unroll
  for (int j = 0; j < 6; j++) {
    v[j] = xr[lane + 64 * j];
    s += v[j];
  }
#pragma unroll
  for (int o = 32; o > 0; o >>= 1) s += __shfl_xor(s, o, 64);
  float mean = s * (1.f / 384.f);
  float q = 0.f;
#pragma unroll
  for (int j = 0; j < 6; j++) {
    float d = v[j] - mean;
    q += d * d;
  }
#pragma unroll
  for (int o = 32; o > 0; o >>= 1) q += __shfl_xor(q, o, 64);
  if (lane == 0) {
    stats[2 * row] = mean;
    stats[2 * row + 1] = rsqrtf(q * (1.f / 384.f) + 1e-5f);
  }
}

// ------------------ LN apply -> bf16 hi/lo planes --------------------------
__global__ __launch_bounds__(256) void ln_apply_k(
    const float* __restrict__ x, const float* __restrict__ stats,
    const float* __restrict__ g, const float* __restrict__ b,
    short* __restrict__ oh, short* __restrict__ ol) {
  int idx = blockIdx.x * 256 + threadIdx.x;
  int c = idx % C, m = idx / C;
  float v = (x[idx] - stats[2 * m]) * stats[2 * m + 1] * g[c] + b[c];
  short h, l;
  split_bf16(v, h, l);
  oh[idx] = h;
  ol[idx] = l;
}

// ------------------------ fp32 -> hi/lo plane cast -------------------------
__global__ __launch_bounds__(256) void cast_k(const float* __restrict__ src,
                                              int n, short* __restrict__ oh,
                                              short* __restrict__ ol) {
  int idx = blockIdx.x * 256 + threadIdx.x;
  if (idx >= n) return;
  short h, l;
  split_bf16(src[idx], h, l);
  oh[idx] = h;
  ol[idx] = l;
}

// ----------------------- split-bf16 MFMA GEMM ------------------------------
// out[row,n] = sum_k A[arow_off+row, k]*W[n,k] over row in [0,Mrows).
// A,W as hi/lo bf16 planes (row stride K). 128x128 block, 4 waves of 64x64
// (4x4 16x16x32 MFMA), BK=32. 3 MFMAs per pair: hh + lh + hl.
// ACT: 0 none, 1 lrelu(0.2), 3 combine v*(e1+e2) (full-M buffers, stride C).
// OSPLIT: write hi/lo planes (stride N). Output row = crow_off + row.
template <int ACT, bool BIAS, bool FLIPA, bool OSPLIT>
__global__ __launch_bounds__(256) void mgemm_k(
    const short* __restrict__ Ah, const short* __restrict__ Al, int K,
    const short* __restrict__ Wh, const short* __restrict__ Wl, int N,
    const float* __restrict__ bias, float* __restrict__ Co, int ldc,
    short* __restrict__ Oh, short* __restrict__ Ol,
    const float* __restrict__ e1, const float* __restrict__ e2, int Mrows,
    int arow_off, int crow_off) {
  __shared__ __align__(16) short sAh[128 * 32];
  __shared__ __align__(16) short sAl[128 * 32];
  __shared__ __align__(16) short sBh[128 * 32];
  __shared__ __align__(16) short sBl[128 * 32];
  const int tid = threadIdx.x;
  const int wave = tid >> 6, lane = tid & 63;
  const int m0 = blockIdx.y * 128, n0 = blockIdx.x * 128;
  const int lrow = lane >> 2, lchunk = lane & 3;  // 16 rows x 4 chunks of 16B
  const int wm = (wave >> 1) * 64, wn = (wave & 1) * 64;
  const int frow = lane & 15, fquad = lane >> 4;

  size_t arow[2], wrow[2];
#pragma unroll
  for (int p = 0; p < 2; p++) {
    int r = p * 64 + wave * 16 + lrow;
    int lm = m0 + r;
    if (lm >= Mrows) lm = Mrows - 1;
    int g = arow_off + lm;
    if (FLIPA) {
      int bb = g / T;
      int tt = g - bb * T;
      g = bb * T + (T - 1 - tt);
    }
    arow[p] = (size_t)g * K;
    int gn = n0 + r;
    int sn = gn < N ? gn : N - 1;
    wrow[p] = (size_t)sn * K;
  }

  floatx4 acc[4][4] = {};
  for (int k0 = 0; k0 < K; k0 += 32) {
    if (k0) __syncthreads();
    const int kc = k0 + lchunk * 8;
#pragma unroll
    for (int p = 0; p < 2; p++) {
      short* lb = &sAh[(p * 64 + wave * 16) * 32];
      GLOAD_LDS16(Ah + arow[p] + kc, lb);
      lb = &sAl[(p * 64 + wave * 16) * 32];
      GLOAD_LDS16(Al + arow[p] + kc, lb);
      lb = &sBh[(p * 64 + wave * 16) * 32];
      GLOAD_LDS16(Wh + wrow[p] + kc, lb);
      lb = &sBl[(p * 64 + wave * 16) * 32];
      GLOAD_LDS16(Wl + wrow[p] + kc, lb);
    }
    __syncthreads();
    short8 ah[4], al[4], bh[4], bl[4];
#pragma unroll
    for (int i = 0; i < 4; i++) {
      int ra = (wm + i * 16 + frow) * 32 + fquad * 8;
      int rb = (wn + i * 16 + frow) * 32 + fquad * 8;
      ah[i] = *(const short8*)&sAh[ra];
      al[i] = *(const short8*)&sAl[ra];
      bh[i] = *(const short8*)&sBh[rb];
      bl[i] = *(const short8*)&sBl[rb];
    }
#pragma unroll
    for (int i = 0; i < 4; i++)
#pragma unroll
      for (int j = 0; j < 4; j++) {
        acc[i][j] = __builtin_amdgcn_mfma_f32_16x16x32_bf16(ah[i], bh[j],
                                                            acc[i][j], 0, 0, 0);
        acc[i][j] = __builtin_amdgcn_mfma_f32_16x16x32_bf16(al[i], bh[j],
                                                            acc[i][j], 0, 0, 0);
        acc[i][j] = __builtin_amdgcn_mfma_f32_16x16x32_bf16(ah[i], bl[j],
                                                            acc[i][j], 0, 0, 0);
      }
  }
  // epilogue: C/D layout col(n)=lane&15, row(m)=fquad*4+reg
#pragma unroll
  for (int i = 0; i < 4; i++) {
#pragma unroll
    for (int r = 0; r < 4; r++) {
      int gm = m0 + wm + i * 16 + fquad * 4 + r;
      if (gm >= Mrows) continue;
      int grow = crow_off + gm;
#pragma unroll
      for (int j = 0; j < 4; j++) {
        int gn = n0 + wn + j * 16 + frow;
        float v = acc[i][j][r];
        if constexpr (BIAS) v += bias[gn];
        if constexpr (ACT == 1) v = v >= 0.f ? v : 0.2f * v;
        if constexpr (ACT == 3) {
          size_t o = (size_t)grow * C + gn;
          v = v * (e1[o] + e2[o]);
        }
        if constexpr (OSPLIT) {
          short h, l;
          split_bf16(v, h, l);
          Oh[(size_t)grow * N + gn] = h;
          Ol[(size_t)grow * N + gn] = l;
        } else {
          Co[(size_t)grow * ldc + gn] = v;
        }
      }
    }
  }
}

// ------------------------- fp32 GEMM (small cases) -------------------------
// ACT: 0 none, 2 softplus. Rows local [0, Mrows).
template <int BM, int BN, int BK, int TM, int TN, int ACT, bool BIAS>
__global__ __launch_bounds__((BM / TM) * (BN / TN)) void gemm_k(
    const float* __restrict__ A, int lda, const float* __restrict__ W, int N,
    int K, const float* __restrict__ bias, float* __restrict__ Co, int ldc,
    int Mrows) {
  constexpr int NT = (BM / TM) * (BN / TN);
  constexpr int BNT = BN / TN;
  __shared__ float As[BK][BM + 4];
  __shared__ float Bs[BK][BN + 4];
  const int tid = threadIdx.x;
  const int m0 = blockIdx.y * BM, n0 = blockIdx.x * BN;
  const int tx = tid % BNT, ty = tid / BNT;
  float acc[TM][TN];
#pragma unroll
  for (int i = 0; i < TM; i++)
#pragma unroll
    for (int j = 0; j < TN; j++) acc[i][j] = 0.f;

  constexpr int KT = BK / 4;
  const int lr = tid / KT;
  const int lk = (tid % KT) * 4;
  constexpr int ROWS = NT / KT;

  for (int k0 = 0; k0 < K; k0 += BK) {
#pragma unroll
    for (int p = 0; p < BM / ROWS; p++) {
      int r = p * ROWS + lr;
      int gm = m0 + r;
      float4 v = make_float4(0.f, 0.f, 0.f, 0.f);
      if (gm < Mrows && (k0 + lk) < K)
        v = *(const float4*)(A + (size_t)gm * lda + (k0 + lk));
      As[lk + 0][r] = v.x;
      As[lk + 1][r] = v.y;
      As[lk + 2][r] = v.z;
      As[lk + 3][r] = v.w;
    }
#pragma unroll
    for (int p = 0; p < BN / ROWS; p++) {
      int r = p * ROWS + lr;
      int gn = n0 + r;
      float4 v = make_float4(0.f, 0.f, 0.f, 0.f);
      if (gn < N && (k0 + lk) < K)
        v = *(const float4*)(W + (size_t)gn * K + (k0 + lk));
      Bs[lk + 0][r] = v.x;
      Bs[lk + 1][r] = v.y;
      Bs[lk + 2][r] = v.z;
      Bs[lk + 3][r] = v.w;
    }
    __syncthreads();
#pragma unroll
    for (int kk = 0; kk < BK; kk++) {
      float af[TM], bf[TN];
#pragma unroll
      for (int i = 0; i < TM; i++) af[i] = As[kk][ty * TM + i];
#pragma unroll
      for (int j = 0; j < TN; j++) bf[j] = Bs[kk][tx * TN + j];
#pragma unroll
      for (int i = 0; i < TM; i++)
#pragma unroll
        for (int j = 0; j < TN; j++) acc[i][j] += af[i] * bf[j];
    }
    __syncthreads();
  }
#pragma unroll
  for (int i = 0; i < TM; i++) {
    int gm = m0 + ty * TM + i;
    if (gm >= Mrows) continue;
#pragma unroll
    for (int j = 0; j < TN; j++) {
      int gn = n0 + tx * TN + j;
      if (gn >= N) continue;
      float v = acc[i][j];
      if constexpr (BIAS) v += bias[gn];
      if constexpr (ACT == 2) v = (v > 20.f) ? v : log1pf(expf(v));
      Co[(size_t)gm * ldc + gn] = v;
    }
  }
}

// --------------------------- depthwise conv + silu -------------------------
// Half-batch local buffers.
__global__ __launch_bounds__(256) void conv_k(const float* __restrict__ xz,
                                              const float* __restrict__ cw,
                                              const float* __restrict__ cb,
                                              float* __restrict__ xc) {
  int idx = blockIdx.x * 256 + threadIdx.x;  // [0, MH*DI)
  int d = idx % DI;
  int m = idx / DI;
  int b = m / T, t = m - b * T;
  const float* base = xz + (size_t)b * T * XZdim + d;
  float a = cb[d];
#pragma unroll
  for (int j = 0; j < 4; j++) {
    int tt = t - 3 + j;
    if (tt >= 0) a += base[(size_t)tt * XZdim] * cw[d * 4 + j];
  }
  xc[(size_t)m * DI + d] = a / (1.f + __expf(-a));
}

// ----------------------- chunked selective scan ----------------------------
// Half-batch local; blockIdx.z = local batch in [0,HB).
__global__ __launch_bounds__(256) void scan_p1_k(
    const float* __restrict__ xzb, const float* __restrict__ xcb,
    const float* __restrict__ xdbl, const float* __restrict__ alog,
    float* __restrict__ hchk, float* __restrict__ pchk) {
  int d = blockIdx.x * 256 + threadIdx.x;
  int ch = blockIdx.y, b = blockIdx.z;
  float A[DSTATE], h[DSTATE];
#pragma unroll
  for (int s = 0; s < DSTATE; s++) {
    A[s] = -expf(alog[d * DSTATE + s]);
    h[s] = 0.f;
  }
  const int t0 = ch * TC;
  const float* xzr = xzb + ((size_t)b * T + t0) * XZdim;
  const float* xcr = xcb + ((size_t)b * T + t0) * DI;
  const float* xdr = xdbl + ((size_t)b * T + t0) * ND;
  float sdt = 0.f;
  for (int t = 0; t < TC; t++) {
    float dt = xzr[(size_t)t * XZdim + d];
    float xv = xcr[(size_t)t * DI + d];
    float dx = dt * xv;
    const float* bvec = xdr + (size_t)t * ND + DTR;
    sdt += dt;
#pragma unroll
    for (int s = 0; s < DSTATE; s++) {
      float e = __expf(dt * A[s]);
      h[s] = h[s] * e + dx * bvec[s];
    }
  }
  size_t o = ((size_t)(b * NCHUNK + ch) * DSTATE) * DI + d;
#pragma unroll
  for (int s = 0; s < DSTATE; s++) {
    hchk[o + (size_t)s * DI] = h[s];
    pchk[o + (size_t)s * DI] = __expf(A[s] * sdt);
  }
}

__global__ __launch_bounds__(256) void scan_p2_k(float* __restrict__ hchk,
                                                 const float* __restrict__ pchk) {
  int idx = blockIdx.x * 256 + threadIdx.x;  // [0, HB*DI)
  int b = idx / DI, d = idx - b * DI;
  float hin[DSTATE];
#pragma unroll
  for (int s = 0; s < DSTATE; s++) hin[s] = 0.f;
  for (int ch = 0; ch < NCHUNK; ch++) {
    size_t o = ((size_t)(b * NCHUNK + ch) * DSTATE) * DI + d;
#pragma unroll
    for (int s = 0; s < DSTATE; s++) {
      float P = pchk[o + (size_t)s * DI];
      float hl = hchk[o + (size_t)s * DI];
      hchk[o + (size_t)s * DI] = hin[s];
      hin[s] = P * hin[s] + hl;
    }
  }
}

// Phase 3: rescan from true incoming state; y = h.C + D*x, gated silu(z);
// emit bf16 hi/lo planes (half-local) for the out_proj MFMA GEMM.
__global__ __launch_bounds__(256) void scan_p3_k(
    const float* __restrict__ xzb, const float* __restrict__ xcb,
    const float* __restrict__ xdbl, const float* __restrict__ alog,
    const float* __restrict__ Dp, const float* __restrict__ hchk,
    short* __restrict__ yh, short* __restrict__ yl) {
  int d = blockIdx.x * 256 + threadIdx.x;
  int ch = blockIdx.y, b = blockIdx.z;
  float A[DSTATE], h[DSTATE];
  size_t o = ((size_t)(b * NCHUNK + ch) * DSTATE) * DI + d;
#pragma unroll
  for (int s = 0; s < DSTATE; s++) {
    A[s] = -expf(alog[d * DSTATE + s]);
    h[s] = hchk[o + (size_t)s * DI];
  }
  float Dd = Dp[d];
  const int t0 = ch * TC;
  const float* xzr = xzb + ((size_t)b * T + t0) * XZdim;
  const float* xcr = xcb + ((size_t)b * T + t0) * DI;
  const float* xdr = xdbl + ((size_t)b * T + t0) * ND;
  for (int t = 0; t < TC; t++) {
    float dt = xzr[(size_t)t * XZdim + d];
    float xv = xcr[(size_t)t * DI + d];
    float zv = xzr[(size_t)t * XZdim + DI + d];
    float dx = dt * xv;
    float accv = 0.f;
    const float* bc = xdr + (size_t)t * ND + DTR;
#pragma unroll
    for (int s = 0; s < DSTATE; s++) {
      float e = __expf(dt * A[s]);
      h[s] = h[s] * e + dx * bc[s];
      accv += h[s] * bc[DSTATE + s];
    }
    float y = accv + Dd * xv;
    float sz = zv / (1.f + __expf(-zv));
    float v = y * sz;
    short hh, ll;
    split_bf16(v, hh, ll);
    size_t oi = ((size_t)(b * T + t0 + t)) * DI + d;
    yh[oi] = hh;
    yl[oi] = ll;
  }
}

// --------------------------- final LN + scatter ----------------------------
__device__ __forceinline__ size_t out_index(int b, int t, int c) {
  if (t < NTOK) {
    int g_ = t >> 6, p = t & 63;
    int sec = g_ / 5, s = g_ % 5;
    return (size_t)sec * SEC_SZ + (((size_t)(b * 5 + s) * C + c) << 6) + p;
  }
  return 3 * SEC_SZ + ((size_t)b * 2 + (t - NTOK)) * C + c;
}

__global__ __launch_bounds__(128) void ln_scatter_k(const float* __restrict__ x,
                                                    const float* __restrict__ g,
                                                    const float* __restrict__ bb,
                                                    float* __restrict__ out) {
  int m = blockIdx.x, tid = threadIdx.x;
  int b = m / T, t = m - b * T;
  const float* xr = x + (size_t)m * C;
  float v0 = xr[tid], v1 = xr[tid + 128], v2 = xr[tid + 256];
  __shared__ float sm2[2];
  int wid = tid >> 6, lane = tid & 63;
  float s = v0 + v1 + v2;
#pragma unroll
  for (int o = 32; o > 0; o >>= 1) s += __shfl_xor(s, o, 64);
  if (lane == 0) sm2[wid] = s;
  __syncthreads();
  float mean = (sm2[0] + sm2[1]) * (1.f / 384.f);
  __syncthreads();
  float d0 = v0 - mean, d1 = v1 - mean, d2 = v2 - mean;
  float q = d0 * d0 + d1 * d1 + d2 * d2;
#pragma unroll
  for (int o = 32; o > 0; o >>= 1) q += __shfl_xor(q, o, 64);
  if (lane == 0) sm2[wid] = q;
  __syncthreads();
  float rstd = rsqrtf((sm2[0] + sm2[1]) * (1.f / 384.f) + 1e-5f);
  float vv[3] = {v0, v1, v2};
#pragma unroll
  for (int j = 0; j < 3; j++) {
    int c = tid + j * 128;
    out[out_index(b, t, c)] = (vv[j] - mean) * rstd * g[c] + bb[c];
  }
}

// --------------------------------- launch ----------------------------------
extern "C" void kernel_launch(void* const* d_in, const int* in_sizes, int n_in,
                              void* d_out, int out_size, void* d_ws,
                              size_t ws_size, hipStream_t stream) {
  const float* image = (const float*)d_in[0];
  const float* lidar = (const float*)d_in[1];
  const float* radar = (const float*)d_in[2];
  const float* gps = (const float*)d_in[3];
  const float* pe = (const float*)d_in[4];
  const float* ln1g = (const float*)d_in[5];
  const float* ln1b = (const float*)d_in[6];
  const float* fc1w = (const float*)d_in[7];
  const float* fc1b = (const float*)d_in[8];
  const float* fc2w = (const float*)d_in[9];
  const float* fc2b_ = (const float*)d_in[10];
  const float* inw = (const float*)d_in[11];
  const float* cw = (const float*)d_in[12];
  const float* cb = (const float*)d_in[13];
  const float* xw = (const float*)d_in[14];
  const float* dtw = (const float*)d_in[15];
  const float* dtb = (const float*)d_in[16];
  const float* alog = (const float*)d_in[17];
  const float* Dp = (const float*)d_in[18];
  const float* ow = (const float*)d_in[19];
  const float* lnfg = (const float*)d_in[20];
  const float* lnfb = (const float*)d_in[21];
  float* out = (float*)d_out;

  // ---------------- workspace carve-up (58,559,424 floats = 234.2 MB) ------
  constexpr size_t MC = (size_t)M * C;  // 5,910,528
  float* ws = (float*)d_ws;
  float* x = ws;                         // MC
  float* fcb = x + MC;                   // MC
  float* fm = fcb + MC;                  // MC (aliased by ln planes)
  float* x1f = fm + MC;                  // MC (x1 planes)
  float* yf = x1f + MC;                  // MC (y planes, half-local)
  float* xz_h = yf + MC;                 // MH*1536 = 11,821,056
  float* xc_h = xz_h + (size_t)MH * XZdim;  // MH*768
  float* xdbl_h = xc_h + (size_t)MH * DI;   // MH*56
  float* stats = xdbl_h + (size_t)MH * ND;  // 2*M
  constexpr size_t CHK_H = (size_t)HB * NCHUNK * DSTATE * DI;  // 1,277,952
  float* hchk = stats + (size_t)2 * M;
  float* pchk = hchk + CHK_H;
  float* wpl = pchk + CHK_H;

  short* lnh = (short*)fm;  // alias: ln planes dead before fm written
  short* lnl = lnh + MC;
  short* x1h = (short*)x1f;
  short* x1l = x1h + MC;
  short* yh = (short*)yf;
  short* yl = yh + (size_t)MH * DI;

  constexpr size_t WSZ1 = (size_t)NLAYER * C * C;          // 589,824
  constexpr size_t WSZI = (size_t)NLAYER * 2 * 2 * DI * C; // 4,718,592
  constexpr size_t WSZO = (size_t)NLAYER * 2 * C * DI;     // 2,359,296
  short* wf1h = (short*)wpl;
  short* wf1l = wf1h + WSZ1;
  short* wf2h = wf1l + WSZ1;
  short* wf2l = wf2h + WSZ1;
  short* winh = wf2l + WSZ1;
  short* winl = winh + WSZI;
  short* wowh = winl + WSZI;
  short* wowl = wowh + WSZO;

  // ---------------- weight plane casts (once per call) ----------------
  cast_k<<<(int)(WSZ1 / 256), 256, 0, stream>>>(fc1w, (int)WSZ1, wf1h, wf1l);
  cast_k<<<(int)(WSZ1 / 256), 256, 0, stream>>>(fc2w, (int)WSZ1, wf2h, wf2l);
  cast_k<<<(int)(WSZI / 256), 256, 0, stream>>>(inw, (int)WSZI, winh, winl);
  cast_k<<<(int)(WSZO / 256), 256, 0, stream>>>(ow, (int)WSZO, wowh, wowl);

  assemble_k<<<(M * C) / 256, 256, 0, stream>>>(image, lidar, radar, gps, pe, x);

  for (int l = 0; l < NLAYER; l++) {
    ln_stats_k<<<M / 4, 256, 0, stream>>>(x, stats);
    ln_apply_k<<<(M * C) / 256, 256, 0, stream>>>(x, stats, ln1g + l * C,
                                                  ln1b + l * C, lnh, lnl);
    // fc1 = LN(x) @ fc1_w^T + b -> bf16 planes (full M)
    mgemm_k<0, true, false, true><<<dim3(3, 121), 256, 0, stream>>>(
        lnh, lnl, C, wf1h + (size_t)l * C * C, wf1l + (size_t)l * C * C, C,
        fc1b + l * C, nullptr, 0, x1h, x1l, nullptr, nullptr, M, 0, 0);
    // fc2b = lrelu(flip(xfc1) @ fc2_w^T + b) -> fp32 (full M)
    mgemm_k<1, true, true, false><<<dim3(3, 121), 256, 0, stream>>>(
        x1h, x1l, C, wf2h + (size_t)l * C * C, wf2l + (size_t)l * C * C, C,
        fc2b_ + l * C, fcb, C, nullptr, nullptr, nullptr, nullptr, M, 0, 0);
    for (int dir = 0; dir < 2; dir++) {
      size_t wo = (size_t)(l * 2 + dir);
      for (int h = 0; h < 2; h++) {
        const int roff = h * MH;
        // in_proj -> xz_h (dir1 reads time-flipped rows of x1)
        if (dir == 0)
          mgemm_k<0, false, false, false><<<dim3(12, 61), 256, 0, stream>>>(
              x1h, x1l, C, winh + wo * 2 * DI * C, winl + wo * 2 * DI * C,
              2 * DI, nullptr, xz_h, XZdim, nullptr, nullptr, nullptr, nullptr,
              MH, roff, 0);
        else
          mgemm_k<0, false, true, false><<<dim3(12, 61), 256, 0, stream>>>(
              x1h, x1l, C, winh + wo * 2 * DI * C, winl + wo * 2 * DI * C,
              2 * DI, nullptr, xz_h, XZdim, nullptr, nullptr, nullptr, nullptr,
              MH, roff, 0);
        // causal depthwise conv + silu -> xc_h
        conv_k<<<(MH * DI) / 256, 256, 0, stream>>>(
            xz_h, cw + wo * DI * DCONV, cb + wo * DI, xc_h);
        // x_proj -> xdbl_h (fp32 path, N=56)
        gemm_k<64, 64, 16, 4, 4, 0, false><<<dim3(1, 121), 256, 0, stream>>>(
            xc_h, DI, xw + wo * ND * DI, ND, DI, nullptr, xdbl_h, ND, MH);
        // dt = softplus(dt_r @ dtw^T + dtb) -> overwrite dead xh half of xz_h
        gemm_k<128, 128, 16, 8, 8, 2, true><<<dim3(6, 61), 256, 0, stream>>>(
            xdbl_h, ND, dtw + wo * DI * DTR, DI, DTR, dtb + wo * DI, xz_h,
            XZdim, MH);
        // chunked selective scan -> y bf16 planes (half-local)
        scan_p1_k<<<dim3(3, NCHUNK, HB), 256, 0, stream>>>(
            xz_h, xc_h, xdbl_h, alog + wo * DI * DSTATE, hchk, pchk);
        scan_p2_k<<<(HB * DI) / 256, 256, 0, stream>>>(hchk, pchk);
        scan_p3_k<<<dim3(3, NCHUNK, HB), 256, 0, stream>>>(
            xz_h, xc_h, xdbl_h, alog + wo * DI * DSTATE, Dp + wo * DI, hchk,
            yh, yl);
        // out_proj; dir1 fuses combine x = bm*(lrelu_fc2 + fm)
        if (dir == 0)
          mgemm_k<0, false, false, false><<<dim3(3, 61), 256, 0, stream>>>(
              yh, yl, DI, wowh + wo * C * DI, wowl + wo * C * DI, C, nullptr,
              fm, C, nullptr, nullptr, nullptr, nullptr, MH, 0, roff);
        else
          mgemm_k<3, false, false, false><<<dim3(3, 61), 256, 0, stream>>>(
              yh, yl, DI, wowh + wo * C * DI, wowl + wo * C * DI, C, nullptr,
              x, C, nullptr, nullptr, fcb, fm, MH, 0, roff);
      }
    }
  }
  ln_scatter_k<<<M, 128, 0, stream>>>(x, lnfg, lnfb, out);
}

// Round 5
// 5046.297 us; speedup vs baseline: 2.0620x; 1.1150x over previous
//
#include <hip/hip_runtime.h>
#include <cstdint>
#include <cstddef>

// ---------------------------------------------------------------------------
// MambaFusion. R4 (on R3's half-batch split-bf16 MFMA structure):
// - x_proj moved to MFMA (conv emits xc as bf16 hi/lo planes; mgemm N=56).
// - scan_p2 parallelized over (b,s,d): 384 blocks, 13-step recurrence.
// - ln_stats+ln_apply fused (one x read, writes LN planes directly).
// Workspace: 58,872,704 floats = 235.5 MB.
// ---------------------------------------------------------------------------

constexpr int BZv = 16, SEQ = 5, NV = 1;
constexpr int C = 384, DSTATE = 16, DCONV = 4, NLAYER = 4;
constexpr int DI = 768;
constexpr int DTR = 24;
constexpr int NTOK = (NV + 2) * SEQ * 64;  // 960
constexpr int T = NTOK + 2;                // 962
constexpr int M = BZv * T;                 // 15392
constexpr int HB = 8;                      // batches per half
constexpr int MH = HB * T;                 // 7696 rows per half
constexpr int XZdim = 2 * DI;              // 1536
constexpr int ND = DTR + 2 * DSTATE;       // 56
constexpr int NCHUNK = 13, TC = 74;
constexpr size_t SEC_SZ = (size_t)BZv * SEQ * C * 64;

typedef __attribute__((ext_vector_type(8))) short short8;
typedef __attribute__((ext_vector_type(4))) float floatx4;

#define GLOAD_LDS16(g, l)                                        \
  __builtin_amdgcn_global_load_lds(                              \
      (const __attribute__((address_space(1))) void*)(g),        \
      (__attribute__((address_space(3))) void*)(l), 16, 0, 0)

__device__ __forceinline__ void split_bf16(float v, short& hi, short& lo) {
  unsigned u = __float_as_uint(v);
  unsigned hib = u & 0xFFFF0000u;      // truncate to bf16
  float r = v - __uint_as_float(hib);  // exact residual
  hi = (short)(hib >> 16);
  lo = (short)(__float_as_uint(r) >> 16);
}

__device__ __forceinline__ float join_bf16(short h, short l) {
  return __uint_as_float((unsigned)(unsigned short)h << 16) +
         __uint_as_float((unsigned)(unsigned short)l << 16);
}

// ------------------------------ token assembly -----------------------------
__global__ __launch_bounds__(256) void assemble_k(
    const float* __restrict__ img, const float* __restrict__ lid,
    const float* __restrict__ rad, const float* __restrict__ gps,
    const float* __restrict__ pe, float* __restrict__ x) {
  int idx = blockIdx.x * 256 + threadIdx.x;
  int c = idx % C;
  int m = idx / C;
  int b = m / T, t = m - b * T;
  float v;
  if (t < NTOK) {
    int g_ = t >> 6, p = t & 63;
    int sec = g_ / 5, s = g_ % 5;
    int band = (c < 128) ? 0 : (c < 256 ? 1 : 2);
    int which = (band + sec) % 3;
    const float* src = (which == 0) ? img : (which == 1 ? lid : rad);
    v = src[(((size_t)(b * 5 + s) * C + c) << 6) + p];
  } else {
    v = gps[((size_t)b * 2 + (t - NTOK)) * C + c];
  }
  x[idx] = v + pe[(size_t)t * C + c];
}

// -------------------- fused LN (stats + apply -> planes) -------------------
__global__ __launch_bounds__(256) void ln_fused_k(
    const float* __restrict__ x, const float* __restrict__ g,
    const float* __restrict__ b, short* __restrict__ oh,
    short* __restrict__ ol) {
  int row = blockIdx.x * 4 + (threadIdx.x >> 6);
  int lane = threadIdx.x & 63;
  const float* xr = x + (size_t)row * C;
  float v[6];
  float s = 0.f;
#pragma unroll
  for (int j = 0; j < 6; j++) {
    v[j] = xr[lane + 64 * j];
    s += v[j];
  }
#pragma unroll
  for (int o = 32; o > 0; o >>= 1) s += __shfl_xor(s, o, 64);
  float mean = s * (1.f / 384.f);
  float q = 0.f;
#pragma unroll
  for (int j = 0; j < 6; j++) {
    float d = v[j] - mean;
    q += d * d;
  }
#pragma unroll
  for (int o = 32; o > 0; o >>= 1) q += __shfl_xor(q, o, 64);
  float rstd = rsqrtf(q * (1.f / 384.f) + 1e-5f);
#pragma unroll
  for (int j = 0; j < 6; j++) {
    int c = lane + 64 * j;
    float val = (v[j] - mean) * rstd * g[c] + b[c];
    short h, l;
    split_bf16(val, h, l);
    oh[(size_t)row * C + c] = h;
    ol[(size_t)row * C + c] = l;
  }
}

// ------------------------ fp32 -> hi/lo plane cast -------------------------
__global__ __launch_bounds__(256) void cast_k(const float* __restrict__ src,
                                              int n, short* __restrict__ oh,
                                              short* __restrict__ ol) {
  int idx = blockIdx.x * 256 + threadIdx.x;
  if (idx >= n) return;
  short h, l;
  split_bf16(src[idx], h, l);
  oh[idx] = h;
  ol[idx] = l;
}

// ----------------------- split-bf16 MFMA GEMM ------------------------------
// out[row,n] = sum_k A[arow_off+row, k]*W[n,k] over row in [0,Mrows).
// A,W as hi/lo bf16 planes (row stride K). 128x128 block, 4 waves of 64x64
// (4x4 16x16x32 MFMA), BK=32. 3 MFMAs per pair: hh + lh + hl.
// ACT: 0 none, 1 lrelu(0.2), 3 combine v*(e1+e2) (full-M buffers, stride C).
// OSPLIT: write hi/lo planes (stride N). Output row = crow_off + row.
template <int ACT, bool BIAS, bool FLIPA, bool OSPLIT>
__global__ __launch_bounds__(256) void mgemm_k(
    const short* __restrict__ Ah, const short* __restrict__ Al, int K,
    const short* __restrict__ Wh, const short* __restrict__ Wl, int N,
    const float* __restrict__ bias, float* __restrict__ Co, int ldc,
    short* __restrict__ Oh, short* __restrict__ Ol,
    const float* __restrict__ e1, const float* __restrict__ e2, int Mrows,
    int arow_off, int crow_off) {
  __shared__ __align__(16) short sAh[128 * 32];
  __shared__ __align__(16) short sAl[128 * 32];
  __shared__ __align__(16) short sBh[128 * 32];
  __shared__ __align__(16) short sBl[128 * 32];
  const int tid = threadIdx.x;
  const int wave = tid >> 6, lane = tid & 63;
  const int m0 = blockIdx.y * 128, n0 = blockIdx.x * 128;
  const int lrow = lane >> 2, lchunk = lane & 3;  // 16 rows x 4 chunks of 16B
  const int wm = (wave >> 1) * 64, wn = (wave & 1) * 64;
  const int frow = lane & 15, fquad = lane >> 4;

  size_t arow[2], wrow[2];
#pragma unroll
  for (int p = 0; p < 2; p++) {
    int r = p * 64 + wave * 16 + lrow;
    int lm = m0 + r;
    if (lm >= Mrows) lm = Mrows - 1;
    int g = arow_off + lm;
    if (FLIPA) {
      int bb = g / T;
      int tt = g - bb * T;
      g = bb * T + (T - 1 - tt);
    }
    arow[p] = (size_t)g * K;
    int gn = n0 + r;
    int sn = gn < N ? gn : N - 1;
    wrow[p] = (size_t)sn * K;
  }

  floatx4 acc[4][4] = {};
  for (int k0 = 0; k0 < K; k0 += 32) {
    if (k0) __syncthreads();
    const int kc = k0 + lchunk * 8;
#pragma unroll
    for (int p = 0; p < 2; p++) {
      short* lb = &sAh[(p * 64 + wave * 16) * 32];
      GLOAD_LDS16(Ah + arow[p] + kc, lb);
      lb = &sAl[(p * 64 + wave * 16) * 32];
      GLOAD_LDS16(Al + arow[p] + kc, lb);
      lb = &sBh[(p * 64 + wave * 16) * 32];
      GLOAD_LDS16(Wh + wrow[p] + kc, lb);
      lb = &sBl[(p * 64 + wave * 16) * 32];
      GLOAD_LDS16(Wl + wrow[p] + kc, lb);
    }
    __syncthreads();
    short8 ah[4], al[4], bh[4], bl[4];
#pragma unroll
    for (int i = 0; i < 4; i++) {
      int ra = (wm + i * 16 + frow) * 32 + fquad * 8;
      int rb = (wn + i * 16 + frow) * 32 + fquad * 8;
      ah[i] = *(const short8*)&sAh[ra];
      al[i] = *(const short8*)&sAl[ra];
      bh[i] = *(const short8*)&sBh[rb];
      bl[i] = *(const short8*)&sBl[rb];
    }
#pragma unroll
    for (int i = 0; i < 4; i++)
#pragma unroll
      for (int j = 0; j < 4; j++) {
        acc[i][j] = __builtin_amdgcn_mfma_f32_16x16x32_bf16(ah[i], bh[j],
                                                            acc[i][j], 0, 0, 0);
        acc[i][j] = __builtin_amdgcn_mfma_f32_16x16x32_bf16(al[i], bh[j],
                                                            acc[i][j], 0, 0, 0);
        acc[i][j] = __builtin_amdgcn_mfma_f32_16x16x32_bf16(ah[i], bl[j],
                                                            acc[i][j], 0, 0, 0);
      }
  }
  // epilogue: C/D layout col(n)=lane&15, row(m)=fquad*4+reg
#pragma unroll
  for (int i = 0; i < 4; i++) {
#pragma unroll
    for (int r = 0; r < 4; r++) {
      int gm = m0 + wm + i * 16 + fquad * 4 + r;
      if (gm >= Mrows) continue;
      int grow = crow_off + gm;
#pragma unroll
      for (int j = 0; j < 4; j++) {
        int gn = n0 + wn + j * 16 + frow;
        if (gn >= N) continue;
        float v = acc[i][j][r];
        if constexpr (BIAS) v += bias[gn];
        if constexpr (ACT == 1) v = v >= 0.f ? v : 0.2f * v;
        if constexpr (ACT == 3) {
          size_t o = (size_t)grow * C + gn;
          v = v * (e1[o] + e2[o]);
        }
        if constexpr (OSPLIT) {
          short h, l;
          split_bf16(v, h, l);
          Oh[(size_t)grow * N + gn] = h;
          Ol[(size_t)grow * N + gn] = l;
        } else {
          Co[(size_t)grow * ldc + gn] = v;
        }
      }
    }
  }
}

// ------------------------- fp32 GEMM (dt_proj) -----------------------------
// ACT: 0 none, 2 softplus. Rows local [0, Mrows).
template <int BM, int BN, int BK, int TM, int TN, int ACT, bool BIAS>
__global__ __launch_bounds__((BM / TM) * (BN / TN)) void gemm_k(
    const float* __restrict__ A, int lda, const float* __restrict__ W, int N,
    int K, const float* __restrict__ bias, float* __restrict__ Co, int ldc,
    int Mrows) {
  constexpr int NT = (BM / TM) * (BN / TN);
  constexpr int BNT = BN / TN;
  __shared__ float As[BK][BM + 4];
  __shared__ float Bs[BK][BN + 4];
  const int tid = threadIdx.x;
  const int m0 = blockIdx.y * BM, n0 = blockIdx.x * BN;
  const int tx = tid % BNT, ty = tid / BNT;
  float acc[TM][TN];
#pragma unroll
  for (int i = 0; i < TM; i++)
#pragma unroll
    for (int j = 0; j < TN; j++) acc[i][j] = 0.f;

  constexpr int KT = BK / 4;
  const int lr = tid / KT;
  const int lk = (tid % KT) * 4;
  constexpr int ROWS = NT / KT;

  for (int k0 = 0; k0 < K; k0 += BK) {
#pragma unroll
    for (int p = 0; p < BM / ROWS; p++) {
      int r = p * ROWS + lr;
      int gm = m0 + r;
      float4 v = make_float4(0.f, 0.f, 0.f, 0.f);
      if (gm < Mrows && (k0 + lk) < K)
        v = *(const float4*)(A + (size_t)gm * lda + (k0 + lk));
      As[lk + 0][r] = v.x;
      As[lk + 1][r] = v.y;
      As[lk + 2][r] = v.z;
      As[lk + 3][r] = v.w;
    }
#pragma unroll
    for (int p = 0; p < BN / ROWS; p++) {
      int r = p * ROWS + lr;
      int gn = n0 + r;
      float4 v = make_float4(0.f, 0.f, 0.f, 0.f);
      if (gn < N && (k0 + lk) < K)
        v = *(const float4*)(W + (size_t)gn * K + (k0 + lk));
      Bs[lk + 0][r] = v.x;
      Bs[lk + 1][r] = v.y;
      Bs[lk + 2][r] = v.z;
      Bs[lk + 3][r] = v.w;
    }
    __syncthreads();
#pragma unroll
    for (int kk = 0; kk < BK; kk++) {
      float af[TM], bf[TN];
#pragma unroll
      for (int i = 0; i < TM; i++) af[i] = As[kk][ty * TM + i];
#pragma unroll
      for (int j = 0; j < TN; j++) bf[j] = Bs[kk][tx * TN + j];
#pragma unroll
      for (int i = 0; i < TM; i++)
#pragma unroll
        for (int j = 0; j < TN; j++) acc[i][j] += af[i] * bf[j];
    }
    __syncthreads();
  }
#pragma unroll
  for (int i = 0; i < TM; i++) {
    int gm = m0 + ty * TM + i;
    if (gm >= Mrows) continue;
#pragma unroll
    for (int j = 0; j < TN; j++) {
      int gn = n0 + tx * TN + j;
      if (gn >= N) continue;
      float v = acc[i][j];
      if constexpr (BIAS) v += bias[gn];
      if constexpr (ACT == 2) v = (v > 20.f) ? v : log1pf(expf(v));
      Co[(size_t)gm * ldc + gn] = v;
    }
  }
}

// --------------------------- depthwise conv + silu -------------------------
// Half-batch local; emits xc as bf16 hi/lo planes (for MFMA x_proj + scan).
__global__ __launch_bounds__(256) void conv_k(const float* __restrict__ xz,
                                              const float* __restrict__ cw,
                                              const float* __restrict__ cb,
                                              short* __restrict__ xch,
                                              short* __restrict__ xcl) {
  int idx = blockIdx.x * 256 + threadIdx.x;  // [0, MH*DI)
  int d = idx % DI;
  int m = idx / DI;
  int b = m / T, t = m - b * T;
  const float* base = xz + (size_t)b * T * XZdim + d;
  float a = cb[d];
#pragma unroll
  for (int j = 0; j < 4; j++) {
    int tt = t - 3 + j;
    if (tt >= 0) a += base[(size_t)tt * XZdim] * cw[d * 4 + j];
  }
  float v = a / (1.f + __expf(-a));
  short h, l;
  split_bf16(v, h, l);
  xch[(size_t)m * DI + d] = h;
  xcl[(size_t)m * DI + d] = l;
}

// ----------------------- chunked selective scan ----------------------------
// Half-batch local; blockIdx.z = local batch in [0,HB).
__global__ __launch_bounds__(256) void scan_p1_k(
    const float* __restrict__ xzb, const short* __restrict__ xch,
    const short* __restrict__ xcl, const float* __restrict__ xdbl,
    const float* __restrict__ alog, float* __restrict__ hchk,
    float* __restrict__ pchk) {
  int d = blockIdx.x * 256 + threadIdx.x;
  int ch = blockIdx.y, b = blockIdx.z;
  float A[DSTATE], h[DSTATE];
#pragma unroll
  for (int s = 0; s < DSTATE; s++) {
    A[s] = -expf(alog[d * DSTATE + s]);
    h[s] = 0.f;
  }
  const int t0 = ch * TC;
  const float* xzr = xzb + ((size_t)b * T + t0) * XZdim;
  const short* xchr = xch + ((size_t)b * T + t0) * DI;
  const short* xclr = xcl + ((size_t)b * T + t0) * DI;
  const float* xdr = xdbl + ((size_t)b * T + t0) * ND;
  float sdt = 0.f;
  for (int t = 0; t < TC; t++) {
    float dt = xzr[(size_t)t * XZdim + d];
    float xv = join_bf16(xchr[(size_t)t * DI + d], xclr[(size_t)t * DI + d]);
    float dx = dt * xv;
    const float* bvec = xdr + (size_t)t * ND + DTR;
    sdt += dt;
#pragma unroll
    for (int s = 0; s < DSTATE; s++) {
      float e = __expf(dt * A[s]);
      h[s] = h[s] * e + dx * bvec[s];
    }
  }
  size_t o = ((size_t)(b * NCHUNK + ch) * DSTATE) * DI + d;
#pragma unroll
  for (int s = 0; s < DSTATE; s++) {
    hchk[o + (size_t)s * DI] = h[s];
    pchk[o + (size_t)s * DI] = __expf(A[s] * sdt);
  }
}

// Chunk-state propagation, parallel over (b,s,d): 13-step recurrence each.
__global__ __launch_bounds__(256) void scan_p2_k(float* __restrict__ hchk,
                                                 const float* __restrict__ pchk) {
  int idx = blockIdx.x * 256 + threadIdx.x;  // [0, HB*DSTATE*DI)
  int d = idx % DI;
  int rem = idx / DI;
  int s = rem % DSTATE, b = rem / DSTATE;
  float hin = 0.f;
#pragma unroll
  for (int ch = 0; ch < NCHUNK; ch++) {
    size_t o = ((size_t)(b * NCHUNK + ch) * DSTATE + s) * DI + d;
    float P = pchk[o];
    float hl = hchk[o];
    hchk[o] = hin;
    hin = P * hin + hl;
  }
}

// Phase 3: rescan from true incoming state; y = h.C + D*x, gated silu(z);
// emit bf16 hi/lo planes (half-local) for the out_proj MFMA GEMM.
__global__ __launch_bounds__(256) void scan_p3_k(
    const float* __restrict__ xzb, const short* __restrict__ xch,
    const short* __restrict__ xcl, const float* __restrict__ xdbl,
    const float* __restrict__ alog, const float* __restrict__ Dp,
    const float* __restrict__ hchk, short* __restrict__ yh,
    short* __restrict__ yl) {
  int d = blockIdx.x * 256 + threadIdx.x;
  int ch = blockIdx.y, b = blockIdx.z;
  float A[DSTATE], h[DSTATE];
  size_t o = ((size_t)(b * NCHUNK + ch) * DSTATE) * DI + d;
#pragma unroll
  for (int s = 0; s < DSTATE; s++) {
    A[s] = -expf(alog[d * DSTATE + s]);
    h[s] = hchk[o + (size_t)s * DI];
  }
  float Dd = Dp[d];
  const int t0 = ch * TC;
  const float* xzr = xzb + ((size_t)b * T + t0) * XZdim;
  const short* xchr = xch + ((size_t)b * T + t0) * DI;
  const short* xclr = xcl + ((size_t)b * T + t0) * DI;
  const float* xdr = xdbl + ((size_t)b * T + t0) * ND;
  for (int t = 0; t < TC; t++) {
    float dt = xzr[(size_t)t * XZdim + d];
    float xv = join_bf16(xchr[(size_t)t * DI + d], xclr[(size_t)t * DI + d]);
    float zv = xzr[(size_t)t * XZdim + DI + d];
    float dx = dt * xv;
    float accv = 0.f;
    const float* bc = xdr + (size_t)t * ND + DTR;
#pragma unroll
    for (int s = 0; s < DSTATE; s++) {
      float e = __expf(dt * A[s]);
      h[s] = h[s] * e + dx * bc[s];
      accv += h[s] * bc[DSTATE + s];
    }
    float y = accv + Dd * xv;
    float sz = zv / (1.f + __expf(-zv));
    float v = y * sz;
    short hh, ll;
    split_bf16(v, hh, ll);
    size_t oi = ((size_t)(b * T + t0 + t)) * DI + d;
    yh[oi] = hh;
    yl[oi] = ll;
  }
}

// --------------------------- final LN + scatter ----------------------------
__device__ __forceinline__ size_t out_index(int b, int t, int c) {
  if (t < NTOK) {
    int g_ = t >> 6, p = t & 63;
    int sec = g_ / 5, s = g_ % 5;
    return (size_t)sec * SEC_SZ + (((size_t)(b * 5 + s) * C + c) << 6) + p;
  }
  return 3 * SEC_SZ + ((size_t)b * 2 + (t - NTOK)) * C + c;
}

__global__ __launch_bounds__(128) void ln_scatter_k(const float* __restrict__ x,
                                                    const float* __restrict__ g,
                                                    const float* __restrict__ bb,
                                                    float* __restrict__ out) {
  int m = blockIdx.x, tid = threadIdx.x;
  int b = m / T, t = m - b * T;
  const float* xr = x + (size_t)m * C;
  float v0 = xr[tid], v1 = xr[tid + 128], v2 = xr[tid + 256];
  __shared__ float sm2[2];
  int wid = tid >> 6, lane = tid & 63;
  float s = v0 + v1 + v2;
#pragma unroll
  for (int o = 32; o > 0; o >>= 1) s += __shfl_xor(s, o, 64);
  if (lane == 0) sm2[wid] = s;
  __syncthreads();
  float mean = (sm2[0] + sm2[1]) * (1.f / 384.f);
  __syncthreads();
  float d0 = v0 - mean, d1 = v1 - mean, d2 = v2 - mean;
  float q = d0 * d0 + d1 * d1 + d2 * d2;
#pragma unroll
  for (int o = 32; o > 0; o >>= 1) q += __shfl_xor(q, o, 64);
  if (lane == 0) sm2[wid] = q;
  __syncthreads();
  float rstd = rsqrtf((sm2[0] + sm2[1]) * (1.f / 384.f) + 1e-5f);
  float vv[3] = {v0, v1, v2};
#pragma unroll
  for (int j = 0; j < 3; j++) {
    int c = tid + j * 128;
    out[out_index(b, t, c)] = (vv[j] - mean) * rstd * g[c] + bb[c];
  }
}

// --------------------------------- launch ----------------------------------
extern "C" void kernel_launch(void* const* d_in, const int* in_sizes, int n_in,
                              void* d_out, int out_size, void* d_ws,
                              size_t ws_size, hipStream_t stream) {
  const float* image = (const float*)d_in[0];
  const float* lidar = (const float*)d_in[1];
  const float* radar = (const float*)d_in[2];
  const float* gps = (const float*)d_in[3];
  const float* pe = (const float*)d_in[4];
  const float* ln1g = (const float*)d_in[5];
  const float* ln1b = (const float*)d_in[6];
  const float* fc1w = (const float*)d_in[7];
  const float* fc1b = (const float*)d_in[8];
  const float* fc2w = (const float*)d_in[9];
  const float* fc2b_ = (const float*)d_in[10];
  const float* inw = (const float*)d_in[11];
  const float* cw = (const float*)d_in[12];
  const float* cb = (const float*)d_in[13];
  const float* xw = (const float*)d_in[14];
  const float* dtw = (const float*)d_in[15];
  const float* dtb = (const float*)d_in[16];
  const float* alog = (const float*)d_in[17];
  const float* Dp = (const float*)d_in[18];
  const float* ow = (const float*)d_in[19];
  const float* lnfg = (const float*)d_in[20];
  const float* lnfb = (const float*)d_in[21];
  float* out = (float*)d_out;

  // ---------------- workspace carve-up (58,872,704 floats = 235.5 MB) ------
  constexpr size_t MC = (size_t)M * C;  // 5,910,528
  float* ws = (float*)d_ws;
  float* x = ws;                            // MC
  float* fcb = x + MC;                      // MC
  float* fm = fcb + MC;                     // MC (aliased by ln planes)
  float* x1f = fm + MC;                     // MC (x1 planes)
  float* yf = x1f + MC;                     // MC (y planes, half-local)
  float* xz_h = yf + MC;                    // MH*1536
  float* xcp = xz_h + (size_t)MH * XZdim;   // MH*DI (xc hi/lo planes)
  float* xdbl_h = xcp + (size_t)MH * DI;    // MH*56
  constexpr size_t CHK_H = (size_t)HB * NCHUNK * DSTATE * DI;  // 1,277,952
  float* hchk = xdbl_h + (size_t)MH * ND;
  float* pchk = hchk + CHK_H;
  float* wpl = pchk + CHK_H;

  short* lnh = (short*)fm;  // alias: ln planes dead before fm written
  short* lnl = lnh + MC;
  short* x1h = (short*)x1f;
  short* x1l = x1h + MC;
  short* yh = (short*)yf;
  short* yl = yh + (size_t)MH * DI;
  short* xch = (short*)xcp;
  short* xcl = xch + (size_t)MH * DI;

  constexpr size_t WSZ1 = (size_t)NLAYER * C * C;           // 589,824
  constexpr size_t WSZI = (size_t)NLAYER * 2 * 2 * DI * C;  // 4,718,592
  constexpr size_t WSZO = (size_t)NLAYER * 2 * C * DI;      // 2,359,296
  constexpr size_t WSZX = (size_t)NLAYER * 2 * ND * DI;     // 344,064
  short* wf1h = (short*)wpl;
  short* wf1l = wf1h + WSZ1;
  short* wf2h = wf1l + WSZ1;
  short* wf2l = wf2h + WSZ1;
  short* winh = wf2l + WSZ1;
  short* winl = winh + WSZI;
  short* wowh = winl + WSZI;
  short* wowl = wowh + WSZO;
  short* wxh = wowl + WSZO;
  short* wxl = wxh + WSZX;

  // ---------------- weight plane casts (once per call) ----------------
  cast_k<<<(int)(WSZ1 / 256), 256, 0, stream>>>(fc1w, (int)WSZ1, wf1h, wf1l);
  cast_k<<<(int)(WSZ1 / 256), 256, 0, stream>>>(fc2w, (int)WSZ1, wf2h, wf2l);
  cast_k<<<(int)(WSZI / 256), 256, 0, stream>>>(inw, (int)WSZI, winh, winl);
  cast_k<<<(int)(WSZO / 256), 256, 0, stream>>>(ow, (int)WSZO, wowh, wowl);
  cast_k<<<(int)(WSZX / 256), 256, 0, stream>>>(xw, (int)WSZX, wxh, wxl);

  assemble_k<<<(M * C) / 256, 256, 0, stream>>>(image, lidar, radar, gps, pe, x);

  for (int l = 0; l < NLAYER; l++) {
    ln_fused_k<<<M / 4, 256, 0, stream>>>(x, ln1g + l * C, ln1b + l * C, lnh,
                                          lnl);
    // fc1 = LN(x) @ fc1_w^T + b -> bf16 planes (full M)
    mgemm_k<0, true, false, true><<<dim3(3, 121), 256, 0, stream>>>(
        lnh, lnl, C, wf1h + (size_t)l * C * C, wf1l + (size_t)l * C * C, C,
        fc1b + l * C, nullptr, 0, x1h, x1l, nullptr, nullptr, M, 0, 0);
    // fc2b = lrelu(flip(xfc1) @ fc2_w^T + b) -> fp32 (full M)
    mgemm_k<1, true, true, false><<<dim3(3, 121), 256, 0, stream>>>(
        x1h, x1l, C, wf2h + (size_t)l * C * C, wf2l + (size_t)l * C * C, C,
        fc2b_ + l * C, fcb, C, nullptr, nullptr, nullptr, nullptr, M, 0, 0);
    for (int dir = 0; dir < 2; dir++) {
      size_t wo = (size_t)(l * 2 + dir);
      for (int h = 0; h < 2; h++) {
        const int roff = h * MH;
        // in_proj -> xz_h (dir1 reads time-flipped rows of x1)
        if (dir == 0)
          mgemm_k<0, false, false, false><<<dim3(12, 61), 256, 0, stream>>>(
              x1h, x1l, C, winh + wo * 2 * DI * C, winl + wo * 2 * DI * C,
              2 * DI, nullptr, xz_h, XZdim, nullptr, nullptr, nullptr, nullptr,
              MH, roff, 0);
        else
          mgemm_k<0, false, true, false><<<dim3(12, 61), 256, 0, stream>>>(
              x1h, x1l, C, winh + wo * 2 * DI * C, winl + wo * 2 * DI * C,
              2 * DI, nullptr, xz_h, XZdim, nullptr, nullptr, nullptr, nullptr,
              MH, roff, 0);
        // causal depthwise conv + silu -> xc planes
        conv_k<<<(MH * DI) / 256, 256, 0, stream>>>(
            xz_h, cw + wo * DI * DCONV, cb + wo * DI, xch, xcl);
        // x_proj (MFMA) -> xdbl_h fp32 (N=56)
        mgemm_k<0, false, false, false><<<dim3(1, 61), 256, 0, stream>>>(
            xch, xcl, DI, wxh + wo * ND * DI, wxl + wo * ND * DI, ND, nullptr,
            xdbl_h, ND, nullptr, nullptr, nullptr, nullptr, MH, 0, 0);
        // dt = softplus(dt_r @ dtw^T + dtb) -> overwrite dead xh half of xz_h
        gemm_k<128, 128, 16, 8, 8, 2, true><<<dim3(6, 61), 256, 0, stream>>>(
            xdbl_h, ND, dtw + wo * DI * DTR, DI, DTR, dtb + wo * DI, xz_h,
            XZdim, MH);
        // chunked selective scan -> y bf16 planes (half-local)
        scan_p1_k<<<dim3(3, NCHUNK, HB), 256, 0, stream>>>(
            xz_h, xch, xcl, xdbl_h, alog + wo * DI * DSTATE, hchk, pchk);
        scan_p2_k<<<(HB * DSTATE * DI) / 256, 256, 0, stream>>>(hchk, pchk);
        scan_p3_k<<<dim3(3, NCHUNK, HB), 256, 0, stream>>>(
            xz_h, xch, xcl, xdbl_h, alog + wo * DI * DSTATE, Dp + wo * DI,
            hchk, yh, yl);
        // out_proj; dir1 fuses combine x = bm*(lrelu_fc2 + fm)
        if (dir == 0)
          mgemm_k<0, false, false, false><<<dim3(3, 61), 256, 0, stream>>>(
              yh, yl, DI, wowh + wo * C * DI, wowl + wo * C * DI, C, nullptr,
              fm, C, nullptr, nullptr, nullptr, nullptr, MH, 0, roff);
        else
          mgemm_k<3, false, false, false><<<dim3(3, 61), 256, 0, stream>>>(
              yh, yl, DI, wowh + wo * C * DI, wowl + wo * C * DI, C, nullptr,
              x, C, nullptr, nullptr, fcb, fm, MH, 0, roff);
      }
    }
  }
  ln_scatter_k<<<M, 128, 0, stream>>>(x, lnfg, lnfb, out);
}